// Round 14
// baseline (289.512 us; speedup 1.0000x reference)
//
#include <hip/hip_runtime.h>
#include <hip/hip_bf16.h>
#include <stdint.h>

#define DM 1024
#define NHEADS 16
#define DK 64
#define BB 4
#define SS 2048

typedef unsigned short u16;
typedef __bf16 bf16x8 __attribute__((ext_vector_type(8)));
typedef __bf16 bf16x4 __attribute__((ext_vector_type(4)));
typedef float f32x4 __attribute__((ext_vector_type(4)));

#if __has_builtin(__builtin_amdgcn_exp2f)
#define EXP2(x) __builtin_amdgcn_exp2f(x)
#else
#define EXP2(x) exp2f(x)
#endif

static __device__ __forceinline__ u16 f2bf(float f) {
    union { float f; uint32_t u; } v; v.f = f;
    uint32_t r = v.u + 0x7fffu + ((v.u >> 16) & 1u);
    return (u16)(r >> 16);
}

static __device__ __forceinline__ f32x4 mfma16(bf16x8 a, bf16x8 b, f32x4 c) {
    return __builtin_amdgcn_mfma_f32_16x16x32_bf16(a, b, c, 0, 0, 0);
}

// async global->LDS 16B (linear LDS dest: wave-uniform base + lane*16)
static __device__ __forceinline__ void gload16(const u16* g, u16* l) {
    __builtin_amdgcn_global_load_lds((const __attribute__((address_space(1))) void*)g,
                                     (__attribute__((address_space(3))) void*)l, 16, 0, 0);
}

// ---------------- merged prep: weight cvt + X cvt + mask bit-pack ----------------
// R10/R11: keep prep separate (fusing X-cvt or mask-pack into the GEMM both regressed).
#define PREP_W 4096
#define PREP_X 12288
#define PREP_M 2048
__global__ __launch_bounds__(256) void k_prep(const float* __restrict__ wq, const float* __restrict__ wk,
                                              const float* __restrict__ wv, const float* __restrict__ wo,
                                              u16* __restrict__ wout,
                                              const float* __restrict__ xq, const float* __restrict__ xk,
                                              const float* __restrict__ xv, u16* __restrict__ xout,
                                              const int* __restrict__ mask, uint32_t* __restrict__ bits) {
    const int bid = blockIdx.x, tid = threadIdx.x;
    if (bid < PREP_W) {
        int t = bid * 256 + tid;
        int which = t >> 18;
        int off = (t & 0x3FFFF) << 2;
        const float* src = (which == 0) ? wq : (which == 1) ? wk : (which == 2) ? wv : wo;
        float4 v = *(const float4*)(src + off);
        ushort4 o;
        o.x = f2bf(v.x); o.y = f2bf(v.y); o.z = f2bf(v.z); o.w = f2bf(v.w);
        *(ushort4*)(wout + ((size_t)which << 20) + off) = o;
    } else if (bid < PREP_W + PREP_X) {
        int lb = bid - PREP_W;
        int which = lb >> 12;
        const float* src = (which == 0) ? xq : (which == 1) ? xk : xv;
        size_t base = (((size_t)(lb & 4095)) * 256 + tid) * 8;
        float4 v0 = *(const float4*)(src + base);
        float4 v1 = *(const float4*)(src + base + 4);
        union { u16 s[8]; uint4 u; } p;
        p.s[0]=f2bf(v0.x); p.s[1]=f2bf(v0.y); p.s[2]=f2bf(v0.z); p.s[3]=f2bf(v0.w);
        p.s[4]=f2bf(v1.x); p.s[5]=f2bf(v1.y); p.s[6]=f2bf(v1.z); p.s[7]=f2bf(v1.w);
        *(uint4*)(xout + ((size_t)which << 23) + base) = p.u;
    } else {
        int lb = bid - PREP_W - PREP_X;
        int gid = lb * 256 + tid;
        int lane = gid & 63;
        int wv_ = gid >> 6;
        const int nw = (PREP_M * 256) >> 6;
        const long totalInts = (long)BB * SS * SS;
        for (long base = (long)wv_ * 64; base < totalInts; base += (long)nw * 64) {
            int m = mask[base + lane];
            unsigned long long bal = __ballot(m != 0);
            if (lane == 0)  bits[(base >> 5)]     = (uint32_t)bal;
            if (lane == 32) bits[(base >> 5) + 1] = (uint32_t)(bal >> 32);
        }
    }
}

// ---------------- 256x128-tile GEMM: Y = X @ W^T + b ----------------
// 8 waves (512 thr), wave owns 64x64 -> 32 MFMA per K-step per wave on 8 ds_read_b128
// (2x the MFMA:staging ratio of the 128x128/4-wave m97 tile; half the barriers per FLOP).
// MODE 0: Y bf16 [b][h][s][d] scaled by alpha. MODE 1: Y bf16 V^T [b][h][d][s]. MODE 2: f32 [m][n].
template<int MODE>
static __device__ __forceinline__ void gemm256(const u16* __restrict__ X, const u16* __restrict__ W,
                                               const float* __restrict__ bias, void* __restrict__ Yv,
                                               float alpha, int tile, int tid,
                                               u16* __restrict__ Ab, u16* __restrict__ Bb) {
    const int lane = tid & 63, w = tid >> 6;
    const int wr = w >> 1, wc = w & 1;
    const int lrow = lane & 15, lgrp = lane >> 4;
    const int m0 = (tile >> 3) * 256;
    const int n0 = (tile & 7) * 128;
    const int srow = tid >> 2;          // 0..127
    const int scol = (tid & 3) * 8;

    f32x4 acc[4][4] = {};

    for (int kk = 0; kk < DM; kk += 32) {
        gload16(X + (size_t)(m0 + srow) * DM + kk + scol,       &Ab[tid * 8]);
        gload16(X + (size_t)(m0 + 128 + srow) * DM + kk + scol, &Ab[4096 + tid * 8]);
        gload16(W + (size_t)(n0 + srow) * DM + kk + scol,       &Bb[tid * 8]);
        __syncthreads();
        bf16x8 af[4], bfr[4];
#pragma unroll
        for (int i = 0; i < 4; ++i)
            af[i] = *(const bf16x8*)&Ab[(wr * 64 + i * 16 + lrow) * 32 + lgrp * 8];
#pragma unroll
        for (int j = 0; j < 4; ++j)
            bfr[j] = *(const bf16x8*)&Bb[(wc * 64 + j * 16 + lrow) * 32 + lgrp * 8];
#pragma unroll
        for (int i = 0; i < 4; ++i)
#pragma unroll
            for (int j = 0; j < 4; ++j)
                acc[i][j] = mfma16(af[i], bfr[j], acc[i][j]);
        __syncthreads();
    }

#pragma unroll
    for (int j = 0; j < 4; ++j) {
        int n = n0 + wc * 64 + j * 16 + lrow;
        float bv_ = bias[n];
        int h = n >> 6, d = n & 63;
#pragma unroll
        for (int i = 0; i < 4; ++i) {
            int mbase = m0 + wr * 64 + i * 16 + (lgrp << 2);
            if (MODE == 0) {
                u16* Y = (u16*)Yv;
#pragma unroll
                for (int r = 0; r < 4; ++r) {
                    int m = mbase + r;
                    int b = m >> 11, s = m & 2047;
                    Y[(((size_t)(b * NHEADS + h) * SS) + s) * DK + d] = f2bf((acc[i][j][r] + bv_) * alpha);
                }
            } else if (MODE == 1) {
                int b = mbase >> 11, s = mbase & 2047;
                ushort4 o;
                o.x = f2bf(acc[i][j][0] + bv_);
                o.y = f2bf(acc[i][j][1] + bv_);
                o.z = f2bf(acc[i][j][2] + bv_);
                o.w = f2bf(acc[i][j][3] + bv_);
                *(ushort4*)&((u16*)Yv)[(((size_t)(b * NHEADS + h) * DK) + d) * SS + s] = o;
            } else {
                float* Y = (float*)Yv;
#pragma unroll
                for (int r = 0; r < 4; ++r)
                    Y[(size_t)(mbase + r) * DM + n] = acc[i][j][r] + bv_;
            }
        }
    }
}

// merged QKV: 768 blocks, sel = bid>>8 in {0:Q, 1:K, 2:V^T}
__global__ __launch_bounds__(512, 4) void k_projqkv(const u16* __restrict__ Xq, const u16* __restrict__ Xk,
                                                    const u16* __restrict__ Xv, const u16* __restrict__ Wb,
                                                    const float* __restrict__ bq, const float* __restrict__ bk,
                                                    const float* __restrict__ bv,
                                                    u16* __restrict__ Qw, u16* __restrict__ Kw,
                                                    u16* __restrict__ Vw, float qscale) {
    __shared__ u16 Ab[256 * 32];
    __shared__ u16 Bb[128 * 32];
    const int sel = blockIdx.x >> 8;
    const int tile = blockIdx.x & 255;
    if (sel == 0)      gemm256<0>(Xq, Wb,               bq, Qw, qscale, tile, threadIdx.x, Ab, Bb);
    else if (sel == 1) gemm256<0>(Xk, Wb + (1u << 20),  bk, Kw, 1.0f,   tile, threadIdx.x, Ab, Bb);
    else               gemm256<1>(Xv, Wb + (2u << 20),  bv, Vw, 1.0f,   tile, threadIdx.x, Ab, Bb);
}

// output projection: 256 blocks
__global__ __launch_bounds__(512, 4) void k_oproj(const u16* __restrict__ X, const u16* __restrict__ W,
                                                  const float* __restrict__ bias, float* __restrict__ out) {
    __shared__ u16 Ab[256 * 32];
    __shared__ u16 Bb[128 * 32];
    gemm256<2>(X, W, bias, out, 1.0f, blockIdx.x, threadIdx.x, Ab, Bb);
}

// ---------------- flash attention: R8 version (best measured: 121.4 us) ----------------
// 8 waves x 16 q-rows; KVBLK=64 double-buffered via global_load_lds; padded Pl.
// Plateau evidence: 7 variants (TLP 12/16/24 waves, LDS 48/50K, Pl swizzle, grids 512/1024,
// subs 1/2/4, 3-buffer QK-hoist pipeline R13) all 121-130 us -> structure-stable optimum.
// __launch_bounds__(512,4): do NOT raise min-waves (R6: (512,6) clamped VGPR to 40 -> spill).
#define NT (SS / 64)
__global__ __launch_bounds__(512, 4) void k_attn(const u16* __restrict__ Q, const u16* __restrict__ K,
                                                 const u16* __restrict__ VT, const uint32_t* __restrict__ mbits,
                                                 u16* __restrict__ ctx) {
    __shared__ u16 Kt[2][64 * 64];
    __shared__ u16 Vt[2][64 * 64];
    __shared__ u16 Pl[8][16][72];
    const int tid = threadIdx.x;
    const int lane = tid & 63, w = tid >> 6;
    const int lrow = lane & 15, lgrp = lane >> 4;
    const int bid = blockIdx.x;
    const int bh = bid & 63;
    const int qt = bid >> 6;          // [0,16)
    const int b = bh >> 4, h = bh & 15;
    const int qbase = qt * 128 + w * 16;

    const u16* Qh = Q + (size_t)bh * SS * DK;
    const u16* Kh = K + (size_t)bh * SS * DK;
    const u16* Vh = VT + (size_t)bh * DK * SS;

    bf16x8 qf0, qf1;
    {
        const u16* p = Qh + (size_t)(qbase + lrow) * DK + lgrp * 8;
        qf0 = *(const bf16x8*)(p);
        qf1 = *(const bf16x8*)(p + 32);
    }

    const uint64_t* mrow = (const uint64_t*)mbits + ((size_t)(b * SS + qbase + lrow)) * (SS / 64);

    union { uint4 u; bf16x8 v; } onesu;
    onesu.u = make_uint4(0x3F803F80u, 0x3F803F80u, 0x3F803F80u, 0x3F803F80u);
    const bf16x8 ones = onesu.v;

    // read-side swizzled col offsets for K/V tiles (elems), constant per lane
    const int swzA = (lgrp * 8) ^ ((lrow & 7) * 8);
    const int swzB = (32 + lgrp * 8) ^ ((lrow & 7) * 8);

    // staging: 512 threads, one 16B gload per thread per tile (K and V each)
    const int srow = tid >> 3;                           // 0..63
    const int ssrc = ((tid & 7) * 8) ^ ((srow & 7) * 8); // inverse swizzle on global col

    f32x4 acc[4] = {};   // [dt]
    f32x4 asum = {};

    // prologue: stage tile 0 into buffer 0
    gload16(Kh + (size_t)srow * DK + ssrc, &Kt[0][tid * 8]);
    gload16(Vh + (size_t)srow * SS + ssrc, &Vt[0][tid * 8]);
    __syncthreads();

    int cur = 0;
    for (int kt = 0; kt < NT; ++kt) {
        // phase A: issue next-tile staging (latency hides under compute)
        if (kt + 1 < NT) {
            gload16(Kh + (size_t)((kt + 1) * 64 + srow) * DK + ssrc, &Kt[cur ^ 1][tid * 8]);
            gload16(Vh + (size_t)srow * SS + (kt + 1) * 64 + ssrc, &Vt[cur ^ 1][tid * 8]);
        }
        const uint64_t wm = mrow[kt];

        const u16* Kc = Kt[cur];
        const u16* Vc = Vt[cur];
        // phase B: QK^T -> exp2+mask -> pack -> A-frags -> asum
        f32x4 st[4] = {};
#pragma unroll
        for (int t = 0; t < 4; ++t) {
            bf16x8 ka = *(const bf16x8*)&Kc[(16 * t + lrow) * 64 + swzA];
            bf16x8 kb = *(const bf16x8*)&Kc[(16 * t + lrow) * 64 + swzB];
            st[t] = mfma16(ka, qf0, st[t]);
            st[t] = mfma16(kb, qf1, st[t]);
        }
#pragma unroll
        for (int t = 0; t < 4; ++t) {
            uint32_t wt = (uint32_t)(wm >> (16 * t + 4 * lgrp));
            bf16x4 pk;
#pragma unroll
            for (int r = 0; r < 4; ++r) {
                float p = EXP2(st[t][r]);
                p = ((wt >> r) & 1u) ? p : 0.0f;
                pk[r] = (__bf16)p;
            }
            *(bf16x4*)&Pl[w][lrow][16 * t + 4 * lgrp] = pk;
        }
        bf16x8 pf0 = *(const bf16x8*)&Pl[w][lrow][lgrp * 8];
        bf16x8 pf1 = *(const bf16x8*)&Pl[w][lrow][32 + lgrp * 8];
        asum = mfma16(pf0, ones, asum);
        asum = mfma16(pf1, ones, asum);
        // PV
#pragma unroll
        for (int dt = 0; dt < 4; ++dt) {
            bf16x8 vf0 = *(const bf16x8*)&Vc[(16 * dt + lrow) * 64 + swzA];
            bf16x8 vf1 = *(const bf16x8*)&Vc[(16 * dt + lrow) * 64 + swzB];
            acc[dt] = mfma16(pf0, vf0, acc[dt]);
            acc[dt] = mfma16(pf1, vf1, acc[dt]);
        }
        // phase C: drain staging + sync all waves before buffer swap
        __syncthreads();
        cur ^= 1;
    }

    // epilogue: normalize (acc and asum share lane->q mapping) and write
#pragma unroll
    for (int r = 0; r < 4; ++r) {
        float li = 1.0f / asum[r];
        int q = qbase + 4 * lgrp + r;
#pragma unroll
        for (int dt = 0; dt < 4; ++dt)
            ctx[((size_t)b * SS + q) * DM + h * 64 + dt * 16 + lrow] = f2bf(acc[dt][r] * li);
    }
}

extern "C" void kernel_launch(void* const* d_in, const int* in_sizes, int n_in,
                              void* d_out, int out_size, void* d_ws, size_t ws_size,
                              hipStream_t stream) {
    const float* query = (const float*)d_in[0];
    const float* key   = (const float*)d_in[1];
    const float* value = (const float*)d_in[2];
    const int*   mask  = (const int*)d_in[3];
    const float* w_q   = (const float*)d_in[4];
    const float* b_q   = (const float*)d_in[5];
    const float* w_k   = (const float*)d_in[6];
    const float* b_k   = (const float*)d_in[7];
    const float* w_v   = (const float*)d_in[8];
    const float* b_v   = (const float*)d_in[9];
    const float* w_o   = (const float*)d_in[10];
    const float* b_o   = (const float*)d_in[11];
    float* out = (float*)d_out;

    char* ws = (char*)d_ws;
    u16*      Wb = (u16*)(ws);                      // 8 MiB: 4 x 1M bf16
    uint32_t* mb = (uint32_t*)(ws + (8u  << 20));   // 2 MiB packed mask bits
    u16*      Xq = (u16*)(ws + (16u << 20));        // 16 MiB each
    u16*      Xk = (u16*)(ws + (32u << 20));
    u16*      Xv = (u16*)(ws + (48u << 20));
    u16*      Qw = (u16*)(ws + (64u << 20));
    u16*      Kw = (u16*)(ws + (80u << 20));
    u16*      Vw = (u16*)(ws + (96u << 20));        // V transposed
    u16*      Cw = (u16*)(ws + (112u << 20));       // context

    const float qscale = 0.125f * 1.4426950408889634f;  // 1/sqrt(64) * log2(e)

    k_prep<<<dim3(PREP_W + PREP_X + PREP_M), dim3(256), 0, stream>>>(
        w_q, w_k, w_v, w_o, Wb, query, key, value, Xq, mask, mb);
    k_projqkv<<<dim3(768), dim3(512), 0, stream>>>(Xq, Xk, Xv, Wb, b_q, b_k, b_v,
                                                   Qw, Kw, Vw, qscale);
    k_attn<<<dim3(1024), dim3(512), 0, stream>>>(Qw, Kw, Vw, mb, Cw);
    k_oproj<<<dim3(256), dim3(512), 0, stream>>>(Cw, Wb + (3u << 20), b_o, out);
}

// Round 15
// 278.539 us; speedup vs baseline: 1.0394x; 1.0394x over previous
//
#include <hip/hip_runtime.h>
#include <hip/hip_bf16.h>
#include <stdint.h>

#define DM 1024
#define NHEADS 16
#define DK 64
#define BB 4
#define SS 2048

typedef unsigned short u16;
typedef __bf16 bf16x8 __attribute__((ext_vector_type(8)));
typedef __bf16 bf16x4 __attribute__((ext_vector_type(4)));
typedef float f32x4 __attribute__((ext_vector_type(4)));

#if __has_builtin(__builtin_amdgcn_exp2f)
#define EXP2(x) __builtin_amdgcn_exp2f(x)
#else
#define EXP2(x) exp2f(x)
#endif

static __device__ __forceinline__ u16 f2bf(float f) {
    union { float f; uint32_t u; } v; v.f = f;
    uint32_t r = v.u + 0x7fffu + ((v.u >> 16) & 1u);
    return (u16)(r >> 16);
}

static __device__ __forceinline__ f32x4 mfma16(bf16x8 a, bf16x8 b, f32x4 c) {
    return __builtin_amdgcn_mfma_f32_16x16x32_bf16(a, b, c, 0, 0, 0);
}

// async global->LDS 16B (linear LDS dest: wave-uniform base + lane*16)
static __device__ __forceinline__ void gload16(const u16* g, u16* l) {
    __builtin_amdgcn_global_load_lds((const __attribute__((address_space(1))) void*)g,
                                     (__attribute__((address_space(3))) void*)l, 16, 0, 0);
}

// ---------------- merged prep: weight cvt + X cvt + mask bit-pack ----------------
// ~35 us = HBM roofline (217 MB moved). R10/R11: fusing X-cvt or mask-pack into the
// GEMM both regressed (XCD panel re-fetch / L2 thrash) — keep prep separate.
#define PREP_W 4096
#define PREP_X 12288
#define PREP_M 2048
__global__ __launch_bounds__(256) void k_prep(const float* __restrict__ wq, const float* __restrict__ wk,
                                              const float* __restrict__ wv, const float* __restrict__ wo,
                                              u16* __restrict__ wout,
                                              const float* __restrict__ xq, const float* __restrict__ xk,
                                              const float* __restrict__ xv, u16* __restrict__ xout,
                                              const int* __restrict__ mask, uint32_t* __restrict__ bits) {
    const int bid = blockIdx.x, tid = threadIdx.x;
    if (bid < PREP_W) {
        int t = bid * 256 + tid;
        int which = t >> 18;
        int off = (t & 0x3FFFF) << 2;
        const float* src = (which == 0) ? wq : (which == 1) ? wk : (which == 2) ? wv : wo;
        float4 v = *(const float4*)(src + off);
        ushort4 o;
        o.x = f2bf(v.x); o.y = f2bf(v.y); o.z = f2bf(v.z); o.w = f2bf(v.w);
        *(ushort4*)(wout + ((size_t)which << 20) + off) = o;
    } else if (bid < PREP_W + PREP_X) {
        int lb = bid - PREP_W;
        int which = lb >> 12;
        const float* src = (which == 0) ? xq : (which == 1) ? xk : xv;
        size_t base = (((size_t)(lb & 4095)) * 256 + tid) * 8;
        float4 v0 = *(const float4*)(src + base);
        float4 v1 = *(const float4*)(src + base + 4);
        union { u16 s[8]; uint4 u; } p;
        p.s[0]=f2bf(v0.x); p.s[1]=f2bf(v0.y); p.s[2]=f2bf(v0.z); p.s[3]=f2bf(v0.w);
        p.s[4]=f2bf(v1.x); p.s[5]=f2bf(v1.y); p.s[6]=f2bf(v1.z); p.s[7]=f2bf(v1.w);
        *(uint4*)(xout + ((size_t)which << 23) + base) = p.u;
    } else {
        int lb = bid - PREP_W - PREP_X;
        int gid = lb * 256 + tid;
        int lane = gid & 63;
        int wv_ = gid >> 6;
        const int nw = (PREP_M * 256) >> 6;
        const long totalInts = (long)BB * SS * SS;
        for (long base = (long)wv_ * 64; base < totalInts; base += (long)nw * 64) {
            int m = mask[base + lane];
            unsigned long long bal = __ballot(m != 0);
            if (lane == 0)  bits[(base >> 5)]     = (uint32_t)bal;
            if (lane == 32) bits[(base >> 5) + 1] = (uint32_t)(bal >> 32);
        }
    }
}

// ---------------- merged QKV projection: Y = X @ W^T + b (128x128 tile, 4 waves) ----------------
// R14: 256x128/8-wave tile regressed (N=1024 is narrow -> grid 768/256 blocks starves CUs;
// oproj fell to 1 block/CU). 128x128 at 512 blocks = 2/CU is the right shape here.
// bid>>9 selects {0:Q scatter(alpha), 1:K scatter, 2:V transposed}.
__global__ __launch_bounds__(256) void k_projqkv(const u16* __restrict__ Xq, const u16* __restrict__ Xk,
                                                 const u16* __restrict__ Xv, const u16* __restrict__ Wb,
                                                 const float* __restrict__ bq, const float* __restrict__ bk,
                                                 const float* __restrict__ bv,
                                                 u16* __restrict__ Qw, u16* __restrict__ Kw,
                                                 u16* __restrict__ Vw, float qscale) {
    __shared__ u16 Ab[128 * 32];
    __shared__ u16 Bb[128 * 32];
    const int sel = blockIdx.x >> 9;
    const int tile = blockIdx.x & 511;
    const u16* X = (sel == 0) ? Xq : (sel == 1) ? Xk : Xv;
    const u16* W = Wb + ((size_t)sel << 20);
    const float* bias = (sel == 0) ? bq : (sel == 1) ? bk : bv;
    u16* Y = (sel == 0) ? Qw : (sel == 1) ? Kw : Vw;
    const float alpha = (sel == 0) ? qscale : 1.0f;

    const int tid = threadIdx.x;
    const int lane = tid & 63, wv = tid >> 6;
    const int wr = wv >> 1, wc = wv & 1;
    const int lrow = lane & 15, lgrp = lane >> 4;
    const int m0 = (tile >> 3) * 128;
    const int n0 = (tile & 7) * 128;
    const int trow = tid >> 2;
    const int tk = (tid & 3) * 8;

    f32x4 acc[4][4] = {};

    for (int kk = 0; kk < DM; kk += 32) {
#pragma unroll
        for (int i = 0; i < 2; ++i) {
            gload16(X + (size_t)(m0 + i * 64 + trow) * DM + kk + tk, &Ab[(i * 256 + tid) * 8]);
            gload16(W + (size_t)(n0 + i * 64 + trow) * DM + kk + tk, &Bb[(i * 256 + tid) * 8]);
        }
        __syncthreads();
        bf16x8 af[4], bfr[4];
#pragma unroll
        for (int i = 0; i < 4; ++i)
            af[i] = *(const bf16x8*)&Ab[(wr * 64 + i * 16 + lrow) * 32 + lgrp * 8];
#pragma unroll
        for (int j = 0; j < 4; ++j)
            bfr[j] = *(const bf16x8*)&Bb[(wc * 64 + j * 16 + lrow) * 32 + lgrp * 8];
#pragma unroll
        for (int i = 0; i < 4; ++i)
#pragma unroll
            for (int j = 0; j < 4; ++j)
                acc[i][j] = mfma16(af[i], bfr[j], acc[i][j]);
        __syncthreads();
    }

#pragma unroll
    for (int j = 0; j < 4; ++j) {
        int n = n0 + wc * 64 + j * 16 + lrow;
        float bv_ = bias[n];
        int h = n >> 6, d = n & 63;
#pragma unroll
        for (int i = 0; i < 4; ++i) {
            int mbase = m0 + wr * 64 + i * 16 + (lgrp << 2);
            if (sel != 2) {
#pragma unroll
                for (int r = 0; r < 4; ++r) {
                    int m = mbase + r;
                    int b = m >> 11, s = m & 2047;
                    Y[(((size_t)(b * NHEADS + h) * SS) + s) * DK + d] = f2bf((acc[i][j][r] + bv_) * alpha);
                }
            } else {
                int b = mbase >> 11, s = mbase & 2047;
                ushort4 o;
                o.x = f2bf(acc[i][j][0] + bv_);
                o.y = f2bf(acc[i][j][1] + bv_);
                o.z = f2bf(acc[i][j][2] + bv_);
                o.w = f2bf(acc[i][j][3] + bv_);
                *(ushort4*)&Y[(((size_t)(b * NHEADS + h) * DK) + d) * SS + s] = o;
            }
        }
    }
}

// ---------------- output projection: out(f32) = ctx(bf16) @ Wo^T + b_o ----------------
__global__ __launch_bounds__(256) void k_oproj(const u16* __restrict__ X, const u16* __restrict__ W,
                                               const float* __restrict__ bias, float* __restrict__ out) {
    __shared__ u16 Ab[128 * 32];
    __shared__ u16 Bb[128 * 32];
    const int tid = threadIdx.x;
    const int lane = tid & 63, wv = tid >> 6;
    const int wr = wv >> 1, wc = wv & 1;
    const int lrow = lane & 15, lgrp = lane >> 4;
    const int m0 = (blockIdx.x >> 3) * 128;
    const int n0 = (blockIdx.x & 7) * 128;
    const int trow = tid >> 2;
    const int tk = (tid & 3) * 8;

    f32x4 acc[4][4] = {};

    for (int kk = 0; kk < DM; kk += 32) {
#pragma unroll
        for (int i = 0; i < 2; ++i) {
            gload16(X + (size_t)(m0 + i * 64 + trow) * DM + kk + tk, &Ab[(i * 256 + tid) * 8]);
            gload16(W + (size_t)(n0 + i * 64 + trow) * DM + kk + tk, &Bb[(i * 256 + tid) * 8]);
        }
        __syncthreads();
        bf16x8 af[4], bfr[4];
#pragma unroll
        for (int i = 0; i < 4; ++i)
            af[i] = *(const bf16x8*)&Ab[(wr * 64 + i * 16 + lrow) * 32 + lgrp * 8];
#pragma unroll
        for (int j = 0; j < 4; ++j)
            bfr[j] = *(const bf16x8*)&Bb[(wc * 64 + j * 16 + lrow) * 32 + lgrp * 8];
#pragma unroll
        for (int i = 0; i < 4; ++i)
#pragma unroll
            for (int j = 0; j < 4; ++j)
                acc[i][j] = mfma16(af[i], bfr[j], acc[i][j]);
        __syncthreads();
    }

#pragma unroll
    for (int j = 0; j < 4; ++j) {
        int n = n0 + wc * 64 + j * 16 + lrow;
        float bv = bias[n];
#pragma unroll
        for (int i = 0; i < 4; ++i) {
            int mbase = m0 + wr * 64 + i * 16 + (lgrp << 2);
#pragma unroll
            for (int r = 0; r < 4; ++r)
                out[(size_t)(mbase + r) * DM + n] = acc[i][j][r] + bv;
        }
    }
}

// ---------------- flash attention: R8 version (best measured: 121.4 us) ----------------
// 8 waves x 16 q-rows; KVBLK=64 double-buffered via global_load_lds; padded Pl.
// Plateau evidence: 8 variants (TLP 12/16/24 waves, LDS 48/50K, Pl swizzle, grids 512/1024,
// subs 1/2/4, 3-buffer QK-hoist pipeline) all 121-130 us -> structure-stable optimum.
// __launch_bounds__(512,4): do NOT raise min-waves (R6: (512,6) clamped VGPR to 40 -> spill).
#define NT (SS / 64)
__global__ __launch_bounds__(512, 4) void k_attn(const u16* __restrict__ Q, const u16* __restrict__ K,
                                                 const u16* __restrict__ VT, const uint32_t* __restrict__ mbits,
                                                 u16* __restrict__ ctx) {
    __shared__ u16 Kt[2][64 * 64];
    __shared__ u16 Vt[2][64 * 64];
    __shared__ u16 Pl[8][16][72];
    const int tid = threadIdx.x;
    const int lane = tid & 63, w = tid >> 6;
    const int lrow = lane & 15, lgrp = lane >> 4;
    const int bid = blockIdx.x;
    const int bh = bid & 63;
    const int qt = bid >> 6;          // [0,16)
    const int b = bh >> 4, h = bh & 15;
    const int qbase = qt * 128 + w * 16;

    const u16* Qh = Q + (size_t)bh * SS * DK;
    const u16* Kh = K + (size_t)bh * SS * DK;
    const u16* Vh = VT + (size_t)bh * DK * SS;

    bf16x8 qf0, qf1;
    {
        const u16* p = Qh + (size_t)(qbase + lrow) * DK + lgrp * 8;
        qf0 = *(const bf16x8*)(p);
        qf1 = *(const bf16x8*)(p + 32);
    }

    const uint64_t* mrow = (const uint64_t*)mbits + ((size_t)(b * SS + qbase + lrow)) * (SS / 64);

    union { uint4 u; bf16x8 v; } onesu;
    onesu.u = make_uint4(0x3F803F80u, 0x3F803F80u, 0x3F803F80u, 0x3F803F80u);
    const bf16x8 ones = onesu.v;

    // read-side swizzled col offsets for K/V tiles (elems), constant per lane
    const int swzA = (lgrp * 8) ^ ((lrow & 7) * 8);
    const int swzB = (32 + lgrp * 8) ^ ((lrow & 7) * 8);

    // staging: 512 threads, one 16B gload per thread per tile (K and V each)
    const int srow = tid >> 3;                           // 0..63
    const int ssrc = ((tid & 7) * 8) ^ ((srow & 7) * 8); // inverse swizzle on global col

    f32x4 acc[4] = {};   // [dt]
    f32x4 asum = {};

    // prologue: stage tile 0 into buffer 0
    gload16(Kh + (size_t)srow * DK + ssrc, &Kt[0][tid * 8]);
    gload16(Vh + (size_t)srow * SS + ssrc, &Vt[0][tid * 8]);
    __syncthreads();

    int cur = 0;
    for (int kt = 0; kt < NT; ++kt) {
        // phase A: issue next-tile staging (latency hides under compute)
        if (kt + 1 < NT) {
            gload16(Kh + (size_t)((kt + 1) * 64 + srow) * DK + ssrc, &Kt[cur ^ 1][tid * 8]);
            gload16(Vh + (size_t)srow * SS + (kt + 1) * 64 + ssrc, &Vt[cur ^ 1][tid * 8]);
        }
        const uint64_t wm = mrow[kt];

        const u16* Kc = Kt[cur];
        const u16* Vc = Vt[cur];
        // phase B: QK^T -> exp2+mask -> pack -> A-frags -> asum
        f32x4 st[4] = {};
#pragma unroll
        for (int t = 0; t < 4; ++t) {
            bf16x8 ka = *(const bf16x8*)&Kc[(16 * t + lrow) * 64 + swzA];
            bf16x8 kb = *(const bf16x8*)&Kc[(16 * t + lrow) * 64 + swzB];
            st[t] = mfma16(ka, qf0, st[t]);
            st[t] = mfma16(kb, qf1, st[t]);
        }
#pragma unroll
        for (int t = 0; t < 4; ++t) {
            uint32_t wt = (uint32_t)(wm >> (16 * t + 4 * lgrp));
            bf16x4 pk;
#pragma unroll
            for (int r = 0; r < 4; ++r) {
                float p = EXP2(st[t][r]);
                p = ((wt >> r) & 1u) ? p : 0.0f;
                pk[r] = (__bf16)p;
            }
            *(bf16x4*)&Pl[w][lrow][16 * t + 4 * lgrp] = pk;
        }
        bf16x8 pf0 = *(const bf16x8*)&Pl[w][lrow][lgrp * 8];
        bf16x8 pf1 = *(const bf16x8*)&Pl[w][lrow][32 + lgrp * 8];
        asum = mfma16(pf0, ones, asum);
        asum = mfma16(pf1, ones, asum);
        // PV
#pragma unroll
        for (int dt = 0; dt < 4; ++dt) {
            bf16x8 vf0 = *(const bf16x8*)&Vc[(16 * dt + lrow) * 64 + swzA];
            bf16x8 vf1 = *(const bf16x8*)&Vc[(16 * dt + lrow) * 64 + swzB];
            acc[dt] = mfma16(pf0, vf0, acc[dt]);
            acc[dt] = mfma16(pf1, vf1, acc[dt]);
        }
        // phase C: drain staging + sync all waves before buffer swap
        __syncthreads();
        cur ^= 1;
    }

    // epilogue: normalize (acc and asum share lane->q mapping) and write
#pragma unroll
    for (int r = 0; r < 4; ++r) {
        float li = 1.0f / asum[r];
        int q = qbase + 4 * lgrp + r;
#pragma unroll
        for (int dt = 0; dt < 4; ++dt)
            ctx[((size_t)b * SS + q) * DM + h * 64 + dt * 16 + lrow] = f2bf(acc[dt][r] * li);
    }
}

extern "C" void kernel_launch(void* const* d_in, const int* in_sizes, int n_in,
                              void* d_out, int out_size, void* d_ws, size_t ws_size,
                              hipStream_t stream) {
    const float* query = (const float*)d_in[0];
    const float* key   = (const float*)d_in[1];
    const float* value = (const float*)d_in[2];
    const int*   mask  = (const int*)d_in[3];
    const float* w_q   = (const float*)d_in[4];
    const float* b_q   = (const float*)d_in[5];
    const float* w_k   = (const float*)d_in[6];
    const float* b_k   = (const float*)d_in[7];
    const float* w_v   = (const float*)d_in[8];
    const float* b_v   = (const float*)d_in[9];
    const float* w_o   = (const float*)d_in[10];
    const float* b_o   = (const float*)d_in[11];
    float* out = (float*)d_out;

    char* ws = (char*)d_ws;
    u16*      Wb = (u16*)(ws);                      // 8 MiB: 4 x 1M bf16
    uint32_t* mb = (uint32_t*)(ws + (8u  << 20));   // 2 MiB packed mask bits
    u16*      Xq = (u16*)(ws + (16u << 20));        // 16 MiB each
    u16*      Xk = (u16*)(ws + (32u << 20));
    u16*      Xv = (u16*)(ws + (48u << 20));
    u16*      Qw = (u16*)(ws + (64u << 20));
    u16*      Kw = (u16*)(ws + (80u << 20));
    u16*      Vw = (u16*)(ws + (96u << 20));        // V transposed
    u16*      Cw = (u16*)(ws + (112u << 20));       // context

    const float qscale = 0.125f * 1.4426950408889634f;  // 1/sqrt(64) * log2(e)

    k_prep<<<dim3(PREP_W + PREP_X + PREP_M), dim3(256), 0, stream>>>(
        w_q, w_k, w_v, w_o, Wb, query, key, value, Xq, mask, mb);
    k_projqkv<<<dim3(1536), dim3(256), 0, stream>>>(Xq, Xk, Xv, Wb, b_q, b_k, b_v,
                                                    Qw, Kw, Vw, qscale);
    k_attn<<<dim3(1024), dim3(512), 0, stream>>>(Qw, Kw, Vw, mb, Cw);
    k_oproj<<<dim3(512), dim3(256), 0, stream>>>(Cw, Wb + (3u << 20), b_o, out);
}

// Round 16
// 264.973 us; speedup vs baseline: 1.0926x; 1.0512x over previous
//
#include <hip/hip_runtime.h>
#include <hip/hip_bf16.h>
#include <stdint.h>

#define DM 1024
#define NHEADS 16
#define DK 64
#define BB 4
#define SS 2048

typedef unsigned short u16;
typedef __bf16 bf16x8 __attribute__((ext_vector_type(8)));
typedef __bf16 bf16x4 __attribute__((ext_vector_type(4)));
typedef float f32x4 __attribute__((ext_vector_type(4)));

#if __has_builtin(__builtin_amdgcn_exp2f)
#define EXP2(x) __builtin_amdgcn_exp2f(x)
#else
#define EXP2(x) exp2f(x)
#endif

static __device__ __forceinline__ u16 f2bf(float f) {
    union { float f; uint32_t u; } v; v.f = f;
    uint32_t r = v.u + 0x7fffu + ((v.u >> 16) & 1u);
    return (u16)(r >> 16);
}

static __device__ __forceinline__ f32x4 mfma16(bf16x8 a, bf16x8 b, f32x4 c) {
    return __builtin_amdgcn_mfma_f32_16x16x32_bf16(a, b, c, 0, 0, 0);
}

// async global->LDS 16B (linear LDS dest: wave-uniform base + lane*16)
static __device__ __forceinline__ void gload16(const u16* g, u16* l) {
    __builtin_amdgcn_global_load_lds((const __attribute__((address_space(1))) void*)g,
                                     (__attribute__((address_space(3))) void*)l, 16, 0, 0);
}

// ---------------- merged prep: weight cvt + X cvt + mask bit-pack ----------------
// ~35 us = HBM roofline (217 MB moved). R10/R11: fusing X-cvt or mask-pack into the
// GEMM both regressed (XCD panel re-fetch / L2 thrash) — keep prep separate.
#define PREP_W 4096
#define PREP_X 12288
#define PREP_M 2048
__global__ __launch_bounds__(256) void k_prep(const float* __restrict__ wq, const float* __restrict__ wk,
                                              const float* __restrict__ wv, const float* __restrict__ wo,
                                              u16* __restrict__ wout,
                                              const float* __restrict__ xq, const float* __restrict__ xk,
                                              const float* __restrict__ xv, u16* __restrict__ xout,
                                              const int* __restrict__ mask, uint32_t* __restrict__ bits) {
    const int bid = blockIdx.x, tid = threadIdx.x;
    if (bid < PREP_W) {
        int t = bid * 256 + tid;
        int which = t >> 18;
        int off = (t & 0x3FFFF) << 2;
        const float* src = (which == 0) ? wq : (which == 1) ? wk : (which == 2) ? wv : wo;
        float4 v = *(const float4*)(src + off);
        ushort4 o;
        o.x = f2bf(v.x); o.y = f2bf(v.y); o.z = f2bf(v.z); o.w = f2bf(v.w);
        *(ushort4*)(wout + ((size_t)which << 20) + off) = o;
    } else if (bid < PREP_W + PREP_X) {
        int lb = bid - PREP_W;
        int which = lb >> 12;
        const float* src = (which == 0) ? xq : (which == 1) ? xk : xv;
        size_t base = (((size_t)(lb & 4095)) * 256 + tid) * 8;
        float4 v0 = *(const float4*)(src + base);
        float4 v1 = *(const float4*)(src + base + 4);
        union { u16 s[8]; uint4 u; } p;
        p.s[0]=f2bf(v0.x); p.s[1]=f2bf(v0.y); p.s[2]=f2bf(v0.z); p.s[3]=f2bf(v0.w);
        p.s[4]=f2bf(v1.x); p.s[5]=f2bf(v1.y); p.s[6]=f2bf(v1.z); p.s[7]=f2bf(v1.w);
        *(uint4*)(xout + ((size_t)which << 23) + base) = p.u;
    } else {
        int lb = bid - PREP_W - PREP_X;
        int gid = lb * 256 + tid;
        int lane = gid & 63;
        int wv_ = gid >> 6;
        const int nw = (PREP_M * 256) >> 6;
        const long totalInts = (long)BB * SS * SS;
        for (long base = (long)wv_ * 64; base < totalInts; base += (long)nw * 64) {
            int m = mask[base + lane];
            unsigned long long bal = __ballot(m != 0);
            if (lane == 0)  bits[(base >> 5)]     = (uint32_t)bal;
            if (lane == 32) bits[(base >> 5) + 1] = (uint32_t)(bal >> 32);
        }
    }
}

// ---------------- 128x128-tile GEMM body, BK=64 (half the barrier-drain events of BK=32) ----------------
// LDS rows are 64 elems (128 B) -> 16-way bank conflict unswizzled; both-sides XOR swizzle
// (rule #21, attn-validated): inverse-swizzled GLOBAL source col, linear gload_lds dest,
// XOR'd read col. 8 consecutive rows -> 8 distinct 16B slots -> conflict-free (2-way across
// lrow+-8 = free, m136). Occupancy unchanged (VGPR-bound 4 blocks/CU; LDS 32 KB < cap).
// MODE 0: Y bf16 [b][h][s][d] scaled. MODE 1: Y bf16 V^T [b][h][d][s]. MODE 2: f32 [m][n].
template<int MODE>
static __device__ __forceinline__ void gemm128(const u16* __restrict__ X, const u16* __restrict__ W,
                                               const float* __restrict__ bias, void* __restrict__ Yv,
                                               float alpha, int tile, int tid,
                                               u16* __restrict__ Ab, u16* __restrict__ Bb) {
    const int lane = tid & 63, w = tid >> 6;
    const int wr = w >> 1, wc = w & 1;
    const int lrow = lane & 15, lgrp = lane >> 4;
    const int m0 = (tile >> 3) * 128;
    const int n0 = (tile & 7) * 128;
    // staging: 4 iters x 32 rows; thread t covers row i*32+(t>>3), col-group (t&7)
    const int sr = tid >> 3;                                  // row within 32-row group
    const int scol = (((tid & 7) ^ (sr & 7)) * 8);            // inverse-swizzled global col
    const int rswz = (lrow & 7) * 8;                          // read-side XOR (elems)

    f32x4 acc[4][4] = {};

    for (int kk = 0; kk < DM; kk += 64) {
#pragma unroll
        for (int i = 0; i < 4; ++i) {
            int row = i * 32 + sr;
            gload16(X + (size_t)(m0 + row) * DM + kk + scol, &Ab[i * 2048 + tid * 8]);
            gload16(W + (size_t)(n0 + row) * DM + kk + scol, &Bb[i * 2048 + tid * 8]);
        }
        __syncthreads();
#pragma unroll
        for (int kh = 0; kh < 2; ++kh) {
            bf16x8 af[4], bfr[4];
#pragma unroll
            for (int i = 0; i < 4; ++i)
                af[i] = *(const bf16x8*)&Ab[(wr * 64 + i * 16 + lrow) * 64 + ((kh * 32 + lgrp * 8) ^ rswz)];
#pragma unroll
            for (int j = 0; j < 4; ++j)
                bfr[j] = *(const bf16x8*)&Bb[(wc * 64 + j * 16 + lrow) * 64 + ((kh * 32 + lgrp * 8) ^ rswz)];
#pragma unroll
            for (int i = 0; i < 4; ++i)
#pragma unroll
                for (int j = 0; j < 4; ++j)
                    acc[i][j] = mfma16(af[i], bfr[j], acc[i][j]);
        }
        __syncthreads();
    }

#pragma unroll
    for (int j = 0; j < 4; ++j) {
        int n = n0 + wc * 64 + j * 16 + lrow;
        float bv_ = bias[n];
        int h = n >> 6, d = n & 63;
#pragma unroll
        for (int i = 0; i < 4; ++i) {
            int mbase = m0 + wr * 64 + i * 16 + (lgrp << 2);
            if (MODE == 0) {
                u16* Y = (u16*)Yv;
#pragma unroll
                for (int r = 0; r < 4; ++r) {
                    int m = mbase + r;
                    int b = m >> 11, s = m & 2047;
                    Y[(((size_t)(b * NHEADS + h) * SS) + s) * DK + d] = f2bf((acc[i][j][r] + bv_) * alpha);
                }
            } else if (MODE == 1) {
                int b = mbase >> 11, s = mbase & 2047;
                ushort4 o;
                o.x = f2bf(acc[i][j][0] + bv_);
                o.y = f2bf(acc[i][j][1] + bv_);
                o.z = f2bf(acc[i][j][2] + bv_);
                o.w = f2bf(acc[i][j][3] + bv_);
                *(ushort4*)&((u16*)Yv)[(((size_t)(b * NHEADS + h) * DK) + d) * SS + s] = o;
            } else {
                float* Y = (float*)Yv;
#pragma unroll
                for (int r = 0; r < 4; ++r)
                    Y[(size_t)(mbase + r) * DM + n] = acc[i][j][r] + bv_;
            }
        }
    }
}

// merged QKV: 1536 blocks, sel = bid>>9 in {0:Q, 1:K, 2:V^T}
__global__ __launch_bounds__(256) void k_projqkv(const u16* __restrict__ Xq, const u16* __restrict__ Xk,
                                                 const u16* __restrict__ Xv, const u16* __restrict__ Wb,
                                                 const float* __restrict__ bq, const float* __restrict__ bk,
                                                 const float* __restrict__ bv,
                                                 u16* __restrict__ Qw, u16* __restrict__ Kw,
                                                 u16* __restrict__ Vw, float qscale) {
    __shared__ u16 Ab[128 * 64];
    __shared__ u16 Bb[128 * 64];
    const int sel = blockIdx.x >> 9;
    const int tile = blockIdx.x & 511;
    if (sel == 0)      gemm128<0>(Xq, Wb,              bq, Qw, qscale, tile, threadIdx.x, Ab, Bb);
    else if (sel == 1) gemm128<0>(Xk, Wb + (1u << 20), bk, Kw, 1.0f,   tile, threadIdx.x, Ab, Bb);
    else               gemm128<1>(Xv, Wb + (2u << 20), bv, Vw, 1.0f,   tile, threadIdx.x, Ab, Bb);
}

// output projection: 512 blocks
__global__ __launch_bounds__(256) void k_oproj(const u16* __restrict__ X, const u16* __restrict__ W,
                                               const float* __restrict__ bias, float* __restrict__ out) {
    __shared__ u16 Ab[128 * 64];
    __shared__ u16 Bb[128 * 64];
    gemm128<2>(X, W, bias, out, 1.0f, blockIdx.x, threadIdx.x, Ab, Bb);
}

// ---------------- flash attention: R8 version (best measured: 121.4 us) ----------------
// 8 waves x 16 q-rows; KVBLK=64 double-buffered via global_load_lds; padded Pl.
// Plateau evidence: 8 variants (TLP 12/16/24 waves, LDS 48/50K, Pl swizzle, grids 512/1024,
// subs 1/2/4, 3-buffer QK-hoist pipeline) all 121-130 us -> structure-stable optimum.
// __launch_bounds__(512,4): do NOT raise min-waves (R6: (512,6) clamped VGPR to 40 -> spill).
#define NT (SS / 64)
__global__ __launch_bounds__(512, 4) void k_attn(const u16* __restrict__ Q, const u16* __restrict__ K,
                                                 const u16* __restrict__ VT, const uint32_t* __restrict__ mbits,
                                                 u16* __restrict__ ctx) {
    __shared__ u16 Kt[2][64 * 64];
    __shared__ u16 Vt[2][64 * 64];
    __shared__ u16 Pl[8][16][72];
    const int tid = threadIdx.x;
    const int lane = tid & 63, w = tid >> 6;
    const int lrow = lane & 15, lgrp = lane >> 4;
    const int bid = blockIdx.x;
    const int bh = bid & 63;
    const int qt = bid >> 6;          // [0,16)
    const int b = bh >> 4, h = bh & 15;
    const int qbase = qt * 128 + w * 16;

    const u16* Qh = Q + (size_t)bh * SS * DK;
    const u16* Kh = K + (size_t)bh * SS * DK;
    const u16* Vh = VT + (size_t)bh * DK * SS;

    bf16x8 qf0, qf1;
    {
        const u16* p = Qh + (size_t)(qbase + lrow) * DK + lgrp * 8;
        qf0 = *(const bf16x8*)(p);
        qf1 = *(const bf16x8*)(p + 32);
    }

    const uint64_t* mrow = (const uint64_t*)mbits + ((size_t)(b * SS + qbase + lrow)) * (SS / 64);

    union { uint4 u; bf16x8 v; } onesu;
    onesu.u = make_uint4(0x3F803F80u, 0x3F803F80u, 0x3F803F80u, 0x3F803F80u);
    const bf16x8 ones = onesu.v;

    // read-side swizzled col offsets for K/V tiles (elems), constant per lane
    const int swzA = (lgrp * 8) ^ ((lrow & 7) * 8);
    const int swzB = (32 + lgrp * 8) ^ ((lrow & 7) * 8);

    // staging: 512 threads, one 16B gload per thread per tile (K and V each)
    const int srow = tid >> 3;                           // 0..63
    const int ssrc = ((tid & 7) * 8) ^ ((srow & 7) * 8); // inverse swizzle on global col

    f32x4 acc[4] = {};   // [dt]
    f32x4 asum = {};

    // prologue: stage tile 0 into buffer 0
    gload16(Kh + (size_t)srow * DK + ssrc, &Kt[0][tid * 8]);
    gload16(Vh + (size_t)srow * SS + ssrc, &Vt[0][tid * 8]);
    __syncthreads();

    int cur = 0;
    for (int kt = 0; kt < NT; ++kt) {
        // phase A: issue next-tile staging (latency hides under compute)
        if (kt + 1 < NT) {
            gload16(Kh + (size_t)((kt + 1) * 64 + srow) * DK + ssrc, &Kt[cur ^ 1][tid * 8]);
            gload16(Vh + (size_t)srow * SS + (kt + 1) * 64 + ssrc, &Vt[cur ^ 1][tid * 8]);
        }
        const uint64_t wm = mrow[kt];

        const u16* Kc = Kt[cur];
        const u16* Vc = Vt[cur];
        // phase B: QK^T -> exp2+mask -> pack -> A-frags -> asum
        f32x4 st[4] = {};
#pragma unroll
        for (int t = 0; t < 4; ++t) {
            bf16x8 ka = *(const bf16x8*)&Kc[(16 * t + lrow) * 64 + swzA];
            bf16x8 kb = *(const bf16x8*)&Kc[(16 * t + lrow) * 64 + swzB];
            st[t] = mfma16(ka, qf0, st[t]);
            st[t] = mfma16(kb, qf1, st[t]);
        }
#pragma unroll
        for (int t = 0; t < 4; ++t) {
            uint32_t wt = (uint32_t)(wm >> (16 * t + 4 * lgrp));
            bf16x4 pk;
#pragma unroll
            for (int r = 0; r < 4; ++r) {
                float p = EXP2(st[t][r]);
                p = ((wt >> r) & 1u) ? p : 0.0f;
                pk[r] = (__bf16)p;
            }
            *(bf16x4*)&Pl[w][lrow][16 * t + 4 * lgrp] = pk;
        }
        bf16x8 pf0 = *(const bf16x8*)&Pl[w][lrow][lgrp * 8];
        bf16x8 pf1 = *(const bf16x8*)&Pl[w][lrow][32 + lgrp * 8];
        asum = mfma16(pf0, ones, asum);
        asum = mfma16(pf1, ones, asum);
        // PV
#pragma unroll
        for (int dt = 0; dt < 4; ++dt) {
            bf16x8 vf0 = *(const bf16x8*)&Vc[(16 * dt + lrow) * 64 + swzA];
            bf16x8 vf1 = *(const bf16x8*)&Vc[(16 * dt + lrow) * 64 + swzB];
            acc[dt] = mfma16(pf0, vf0, acc[dt]);
            acc[dt] = mfma16(pf1, vf1, acc[dt]);
        }
        // phase C: drain staging + sync all waves before buffer swap
        __syncthreads();
        cur ^= 1;
    }

    // epilogue: normalize (acc and asum share lane->q mapping) and write
#pragma unroll
    for (int r = 0; r < 4; ++r) {
        float li = 1.0f / asum[r];
        int q = qbase + 4 * lgrp + r;
#pragma unroll
        for (int dt = 0; dt < 4; ++dt)
            ctx[((size_t)b * SS + q) * DM + h * 64 + dt * 16 + lrow] = f2bf(acc[dt][r] * li);
    }
}

extern "C" void kernel_launch(void* const* d_in, const int* in_sizes, int n_in,
                              void* d_out, int out_size, void* d_ws, size_t ws_size,
                              hipStream_t stream) {
    const float* query = (const float*)d_in[0];
    const float* key   = (const float*)d_in[1];
    const float* value = (const float*)d_in[2];
    const int*   mask  = (const int*)d_in[3];
    const float* w_q   = (const float*)d_in[4];
    const float* b_q   = (const float*)d_in[5];
    const float* w_k   = (const float*)d_in[6];
    const float* b_k   = (const float*)d_in[7];
    const float* w_v   = (const float*)d_in[8];
    const float* b_v   = (const float*)d_in[9];
    const float* w_o   = (const float*)d_in[10];
    const float* b_o   = (const float*)d_in[11];
    float* out = (float*)d_out;

    char* ws = (char*)d_ws;
    u16*      Wb = (u16*)(ws);                      // 8 MiB: 4 x 1M bf16
    uint32_t* mb = (uint32_t*)(ws + (8u  << 20));   // 2 MiB packed mask bits
    u16*      Xq = (u16*)(ws + (16u << 20));        // 16 MiB each
    u16*      Xk = (u16*)(ws + (32u << 20));
    u16*      Xv = (u16*)(ws + (48u << 20));
    u16*      Qw = (u16*)(ws + (64u << 20));
    u16*      Kw = (u16*)(ws + (80u << 20));
    u16*      Vw = (u16*)(ws + (96u << 20));        // V transposed
    u16*      Cw = (u16*)(ws + (112u << 20));       // context

    const float qscale = 0.125f * 1.4426950408889634f;  // 1/sqrt(64) * log2(e)

    k_prep<<<dim3(PREP_W + PREP_X + PREP_M), dim3(256), 0, stream>>>(
        w_q, w_k, w_v, w_o, Wb, query, key, value, Xq, mask, mb);
    k_projqkv<<<dim3(1536), dim3(256), 0, stream>>>(Xq, Xk, Xv, Wb, b_q, b_k, b_v,
                                                    Qw, Kw, Vw, qscale);
    k_attn<<<dim3(1024), dim3(512), 0, stream>>>(Qw, Kw, Vw, mb, Cw);
    k_oproj<<<dim3(512), dim3(256), 0, stream>>>(Cw, Wb + (3u << 20), b_o, out);
}

// Round 17
// 254.557 us; speedup vs baseline: 1.1373x; 1.0409x over previous
//
#include <hip/hip_runtime.h>
#include <hip/hip_bf16.h>
#include <stdint.h>

#define DM 1024
#define NHEADS 16
#define DK 64
#define BB 4
#define SS 2048

typedef unsigned short u16;
typedef __bf16 bf16x8 __attribute__((ext_vector_type(8)));
typedef __bf16 bf16x4 __attribute__((ext_vector_type(4)));
typedef float f32x4 __attribute__((ext_vector_type(4)));

#if __has_builtin(__builtin_amdgcn_exp2f)
#define EXP2(x) __builtin_amdgcn_exp2f(x)
#else
#define EXP2(x) exp2f(x)
#endif

static __device__ __forceinline__ u16 f2bf(float f) {
    union { float f; uint32_t u; } v; v.f = f;
    uint32_t r = v.u + 0x7fffu + ((v.u >> 16) & 1u);
    return (u16)(r >> 16);
}

static __device__ __forceinline__ f32x4 mfma16(bf16x8 a, bf16x8 b, f32x4 c) {
    return __builtin_amdgcn_mfma_f32_16x16x32_bf16(a, b, c, 0, 0, 0);
}

// async global->LDS 16B (linear LDS dest: wave-uniform base + lane*16)
static __device__ __forceinline__ void gload16(const u16* g, u16* l) {
    __builtin_amdgcn_global_load_lds((const __attribute__((address_space(1))) void*)g,
                                     (__attribute__((address_space(3))) void*)l, 16, 0, 0);
}

// ---------------- merged prep: weight cvt + X cvt + mask bit-pack ----------------
// ~35 us = HBM roofline (217 MB moved). R10/R11: fusing X-cvt or mask-pack into the
// GEMM both regressed (XCD panel re-fetch / L2 thrash) — keep prep separate.
#define PREP_W 4096
#define PREP_X 12288
#define PREP_M 2048
__global__ __launch_bounds__(256) void k_prep(const float* __restrict__ wq, const float* __restrict__ wk,
                                              const float* __restrict__ wv, const float* __restrict__ wo,
                                              u16* __restrict__ wout,
                                              const float* __restrict__ xq, const float* __restrict__ xk,
                                              const float* __restrict__ xv, u16* __restrict__ xout,
                                              const int* __restrict__ mask, uint32_t* __restrict__ bits) {
    const int bid = blockIdx.x, tid = threadIdx.x;
    if (bid < PREP_W) {
        int t = bid * 256 + tid;
        int which = t >> 18;
        int off = (t & 0x3FFFF) << 2;
        const float* src = (which == 0) ? wq : (which == 1) ? wk : (which == 2) ? wv : wo;
        float4 v = *(const float4*)(src + off);
        ushort4 o;
        o.x = f2bf(v.x); o.y = f2bf(v.y); o.z = f2bf(v.z); o.w = f2bf(v.w);
        *(ushort4*)(wout + ((size_t)which << 20) + off) = o;
    } else if (bid < PREP_W + PREP_X) {
        int lb = bid - PREP_W;
        int which = lb >> 12;
        const float* src = (which == 0) ? xq : (which == 1) ? xk : xv;
        size_t base = (((size_t)(lb & 4095)) * 256 + tid) * 8;
        float4 v0 = *(const float4*)(src + base);
        float4 v1 = *(const float4*)(src + base + 4);
        union { u16 s[8]; uint4 u; } p;
        p.s[0]=f2bf(v0.x); p.s[1]=f2bf(v0.y); p.s[2]=f2bf(v0.z); p.s[3]=f2bf(v0.w);
        p.s[4]=f2bf(v1.x); p.s[5]=f2bf(v1.y); p.s[6]=f2bf(v1.z); p.s[7]=f2bf(v1.w);
        *(uint4*)(xout + ((size_t)which << 23) + base) = p.u;
    } else {
        int lb = bid - PREP_W - PREP_X;
        int gid = lb * 256 + tid;
        int lane = gid & 63;
        int wv_ = gid >> 6;
        const int nw = (PREP_M * 256) >> 6;
        const long totalInts = (long)BB * SS * SS;
        for (long base = (long)wv_ * 64; base < totalInts; base += (long)nw * 64) {
            int m = mask[base + lane];
            unsigned long long bal = __ballot(m != 0);
            if (lane == 0)  bits[(base >> 5)]     = (uint32_t)bal;
            if (lane == 32) bits[(base >> 5) + 1] = (uint32_t)(bal >> 32);
        }
    }
}

// ---------------- 128x128-tile GEMM body, BK=64, XCD-local tile decode ----------------
// BK=64 (R16: half the barrier-drain events, -13.6 us total) with both-sides XOR swizzle
// (rule #21): inverse-swizzled GLOBAL source col, linear gload_lds dest, XOR'd read col.
// Tile decode m = tile&63, n = tile>>6 (T1): an m-row's 8 blocks sit at bid stride 64
// = 0 mod 8 -> SAME XCD; per-XCD working set = 8 A-panels (2 MB) + full W (2 MB) = its
// 4 MB L2. Old n-fastest decode fetched every A-panel on 8 XCDs (R11: FETCH 232 MB).
// MODE 0: Y bf16 [b][h][s][d] scaled. MODE 1: Y bf16 V^T [b][h][d][s]. MODE 2: f32 [m][n].
template<int MODE>
static __device__ __forceinline__ void gemm128(const u16* __restrict__ X, const u16* __restrict__ W,
                                               const float* __restrict__ bias, void* __restrict__ Yv,
                                               float alpha, int tile, int tid,
                                               u16* __restrict__ Ab, u16* __restrict__ Bb) {
    const int lane = tid & 63, w = tid >> 6;
    const int wr = w >> 1, wc = w & 1;
    const int lrow = lane & 15, lgrp = lane >> 4;
    const int m0 = (tile & 63) * 128;        // m-fastest: same-m blocks share an XCD
    const int n0 = (tile >> 6) * 128;
    // staging: 4 iters x 32 rows; thread t covers row i*32+(t>>3), col-group (t&7)
    const int sr = tid >> 3;                                  // row within 32-row group
    const int scol = (((tid & 7) ^ (sr & 7)) * 8);            // inverse-swizzled global col
    const int rswz = (lrow & 7) * 8;                          // read-side XOR (elems)

    f32x4 acc[4][4] = {};

    for (int kk = 0; kk < DM; kk += 64) {
#pragma unroll
        for (int i = 0; i < 4; ++i) {
            int row = i * 32 + sr;
            gload16(X + (size_t)(m0 + row) * DM + kk + scol, &Ab[i * 2048 + tid * 8]);
            gload16(W + (size_t)(n0 + row) * DM + kk + scol, &Bb[i * 2048 + tid * 8]);
        }
        __syncthreads();
#pragma unroll
        for (int kh = 0; kh < 2; ++kh) {
            bf16x8 af[4], bfr[4];
#pragma unroll
            for (int i = 0; i < 4; ++i)
                af[i] = *(const bf16x8*)&Ab[(wr * 64 + i * 16 + lrow) * 64 + ((kh * 32 + lgrp * 8) ^ rswz)];
#pragma unroll
            for (int j = 0; j < 4; ++j)
                bfr[j] = *(const bf16x8*)&Bb[(wc * 64 + j * 16 + lrow) * 64 + ((kh * 32 + lgrp * 8) ^ rswz)];
#pragma unroll
            for (int i = 0; i < 4; ++i)
#pragma unroll
                for (int j = 0; j < 4; ++j)
                    acc[i][j] = mfma16(af[i], bfr[j], acc[i][j]);
        }
        __syncthreads();
    }

#pragma unroll
    for (int j = 0; j < 4; ++j) {
        int n = n0 + wc * 64 + j * 16 + lrow;
        float bv_ = bias[n];
        int h = n >> 6, d = n & 63;
#pragma unroll
        for (int i = 0; i < 4; ++i) {
            int mbase = m0 + wr * 64 + i * 16 + (lgrp << 2);
            if (MODE == 0) {
                u16* Y = (u16*)Yv;
#pragma unroll
                for (int r = 0; r < 4; ++r) {
                    int m = mbase + r;
                    int b = m >> 11, s = m & 2047;
                    Y[(((size_t)(b * NHEADS + h) * SS) + s) * DK + d] = f2bf((acc[i][j][r] + bv_) * alpha);
                }
            } else if (MODE == 1) {
                int b = mbase >> 11, s = mbase & 2047;
                ushort4 o;
                o.x = f2bf(acc[i][j][0] + bv_);
                o.y = f2bf(acc[i][j][1] + bv_);
                o.z = f2bf(acc[i][j][2] + bv_);
                o.w = f2bf(acc[i][j][3] + bv_);
                *(ushort4*)&((u16*)Yv)[(((size_t)(b * NHEADS + h) * DK) + d) * SS + s] = o;
            } else {
                float* Y = (float*)Yv;
#pragma unroll
                for (int r = 0; r < 4; ++r)
                    Y[(size_t)(mbase + r) * DM + n] = acc[i][j][r] + bv_;
            }
        }
    }
}

// merged QKV: 1536 blocks, sel = bid>>9 in {0:Q, 1:K, 2:V^T}
__global__ __launch_bounds__(256) void k_projqkv(const u16* __restrict__ Xq, const u16* __restrict__ Xk,
                                                 const u16* __restrict__ Xv, const u16* __restrict__ Wb,
                                                 const float* __restrict__ bq, const float* __restrict__ bk,
                                                 const float* __restrict__ bv,
                                                 u16* __restrict__ Qw, u16* __restrict__ Kw,
                                                 u16* __restrict__ Vw, float qscale) {
    __shared__ u16 Ab[128 * 64];
    __shared__ u16 Bb[128 * 64];
    const int sel = blockIdx.x >> 9;
    const int tile = blockIdx.x & 511;
    if (sel == 0)      gemm128<0>(Xq, Wb,              bq, Qw, qscale, tile, threadIdx.x, Ab, Bb);
    else if (sel == 1) gemm128<0>(Xk, Wb + (1u << 20), bk, Kw, 1.0f,   tile, threadIdx.x, Ab, Bb);
    else               gemm128<1>(Xv, Wb + (2u << 20), bv, Vw, 1.0f,   tile, threadIdx.x, Ab, Bb);
}

// output projection: 512 blocks
__global__ __launch_bounds__(256) void k_oproj(const u16* __restrict__ X, const u16* __restrict__ W,
                                               const float* __restrict__ bias, float* __restrict__ out) {
    __shared__ u16 Ab[128 * 64];
    __shared__ u16 Bb[128 * 64];
    gemm128<2>(X, W, bias, out, 1.0f, blockIdx.x, threadIdx.x, Ab, Bb);
}

// ---------------- flash attention: R8 version (best measured: 121.4 us) ----------------
// 8 waves x 16 q-rows; KVBLK=64 double-buffered via global_load_lds; padded Pl.
// Plateau evidence: 8 variants (TLP 12/16/24 waves, LDS 48/50K, Pl swizzle, grids 512/1024,
// subs 1/2/4, 3-buffer QK-hoist pipeline) all 121-130 us -> structure-stable optimum.
// __launch_bounds__(512,4): do NOT raise min-waves (R6: (512,6) clamped VGPR to 40 -> spill).
#define NT (SS / 64)
__global__ __launch_bounds__(512, 4) void k_attn(const u16* __restrict__ Q, const u16* __restrict__ K,
                                                 const u16* __restrict__ VT, const uint32_t* __restrict__ mbits,
                                                 u16* __restrict__ ctx) {
    __shared__ u16 Kt[2][64 * 64];
    __shared__ u16 Vt[2][64 * 64];
    __shared__ u16 Pl[8][16][72];
    const int tid = threadIdx.x;
    const int lane = tid & 63, w = tid >> 6;
    const int lrow = lane & 15, lgrp = lane >> 4;
    const int bid = blockIdx.x;
    const int bh = bid & 63;
    const int qt = bid >> 6;          // [0,16)
    const int b = bh >> 4, h = bh & 15;
    const int qbase = qt * 128 + w * 16;

    const u16* Qh = Q + (size_t)bh * SS * DK;
    const u16* Kh = K + (size_t)bh * SS * DK;
    const u16* Vh = VT + (size_t)bh * DK * SS;

    bf16x8 qf0, qf1;
    {
        const u16* p = Qh + (size_t)(qbase + lrow) * DK + lgrp * 8;
        qf0 = *(const bf16x8*)(p);
        qf1 = *(const bf16x8*)(p + 32);
    }

    const uint64_t* mrow = (const uint64_t*)mbits + ((size_t)(b * SS + qbase + lrow)) * (SS / 64);

    union { uint4 u; bf16x8 v; } onesu;
    onesu.u = make_uint4(0x3F803F80u, 0x3F803F80u, 0x3F803F80u, 0x3F803F80u);
    const bf16x8 ones = onesu.v;

    // read-side swizzled col offsets for K/V tiles (elems), constant per lane
    const int swzA = (lgrp * 8) ^ ((lrow & 7) * 8);
    const int swzB = (32 + lgrp * 8) ^ ((lrow & 7) * 8);

    // staging: 512 threads, one 16B gload per thread per tile (K and V each)
    const int srow = tid >> 3;                           // 0..63
    const int ssrc = ((tid & 7) * 8) ^ ((srow & 7) * 8); // inverse swizzle on global col

    f32x4 acc[4] = {};   // [dt]
    f32x4 asum = {};

    // prologue: stage tile 0 into buffer 0
    gload16(Kh + (size_t)srow * DK + ssrc, &Kt[0][tid * 8]);
    gload16(Vh + (size_t)srow * SS + ssrc, &Vt[0][tid * 8]);
    __syncthreads();

    int cur = 0;
    for (int kt = 0; kt < NT; ++kt) {
        // phase A: issue next-tile staging (latency hides under compute)
        if (kt + 1 < NT) {
            gload16(Kh + (size_t)((kt + 1) * 64 + srow) * DK + ssrc, &Kt[cur ^ 1][tid * 8]);
            gload16(Vh + (size_t)srow * SS + (kt + 1) * 64 + ssrc, &Vt[cur ^ 1][tid * 8]);
        }
        const uint64_t wm = mrow[kt];

        const u16* Kc = Kt[cur];
        const u16* Vc = Vt[cur];
        // phase B: QK^T -> exp2+mask -> pack -> A-frags -> asum
        f32x4 st[4] = {};
#pragma unroll
        for (int t = 0; t < 4; ++t) {
            bf16x8 ka = *(const bf16x8*)&Kc[(16 * t + lrow) * 64 + swzA];
            bf16x8 kb = *(const bf16x8*)&Kc[(16 * t + lrow) * 64 + swzB];
            st[t] = mfma16(ka, qf0, st[t]);
            st[t] = mfma16(kb, qf1, st[t]);
        }
#pragma unroll
        for (int t = 0; t < 4; ++t) {
            uint32_t wt = (uint32_t)(wm >> (16 * t + 4 * lgrp));
            bf16x4 pk;
#pragma unroll
            for (int r = 0; r < 4; ++r) {
                float p = EXP2(st[t][r]);
                p = ((wt >> r) & 1u) ? p : 0.0f;
                pk[r] = (__bf16)p;
            }
            *(bf16x4*)&Pl[w][lrow][16 * t + 4 * lgrp] = pk;
        }
        bf16x8 pf0 = *(const bf16x8*)&Pl[w][lrow][lgrp * 8];
        bf16x8 pf1 = *(const bf16x8*)&Pl[w][lrow][32 + lgrp * 8];
        asum = mfma16(pf0, ones, asum);
        asum = mfma16(pf1, ones, asum);
        // PV
#pragma unroll
        for (int dt = 0; dt < 4; ++dt) {
            bf16x8 vf0 = *(const bf16x8*)&Vc[(16 * dt + lrow) * 64 + swzA];
            bf16x8 vf1 = *(const bf16x8*)&Vc[(16 * dt + lrow) * 64 + swzB];
            acc[dt] = mfma16(pf0, vf0, acc[dt]);
            acc[dt] = mfma16(pf1, vf1, acc[dt]);
        }
        // phase C: drain staging + sync all waves before buffer swap
        __syncthreads();
        cur ^= 1;
    }

    // epilogue: normalize (acc and asum share lane->q mapping) and write
#pragma unroll
    for (int r = 0; r < 4; ++r) {
        float li = 1.0f / asum[r];
        int q = qbase + 4 * lgrp + r;
#pragma unroll
        for (int dt = 0; dt < 4; ++dt)
            ctx[((size_t)b * SS + q) * DM + h * 64 + dt * 16 + lrow] = f2bf(acc[dt][r] * li);
    }
}

extern "C" void kernel_launch(void* const* d_in, const int* in_sizes, int n_in,
                              void* d_out, int out_size, void* d_ws, size_t ws_size,
                              hipStream_t stream) {
    const float* query = (const float*)d_in[0];
    const float* key   = (const float*)d_in[1];
    const float* value = (const float*)d_in[2];
    const int*   mask  = (const int*)d_in[3];
    const float* w_q   = (const float*)d_in[4];
    const float* b_q   = (const float*)d_in[5];
    const float* w_k   = (const float*)d_in[6];
    const float* b_k   = (const float*)d_in[7];
    const float* w_v   = (const float*)d_in[8];
    const float* b_v   = (const float*)d_in[9];
    const float* w_o   = (const float*)d_in[10];
    const float* b_o   = (const float*)d_in[11];
    float* out = (float*)d_out;

    char* ws = (char*)d_ws;
    u16*      Wb = (u16*)(ws);                      // 8 MiB: 4 x 1M bf16
    uint32_t* mb = (uint32_t*)(ws + (8u  << 20));   // 2 MiB packed mask bits
    u16*      Xq = (u16*)(ws + (16u << 20));        // 16 MiB each
    u16*      Xk = (u16*)(ws + (32u << 20));
    u16*      Xv = (u16*)(ws + (48u << 20));
    u16*      Qw = (u16*)(ws + (64u << 20));
    u16*      Kw = (u16*)(ws + (80u << 20));
    u16*      Vw = (u16*)(ws + (96u << 20));        // V transposed
    u16*      Cw = (u16*)(ws + (112u << 20));       // context

    const float qscale = 0.125f * 1.4426950408889634f;  // 1/sqrt(64) * log2(e)

    k_prep<<<dim3(PREP_W + PREP_X + PREP_M), dim3(256), 0, stream>>>(
        w_q, w_k, w_v, w_o, Wb, query, key, value, Xq, mask, mb);
    k_projqkv<<<dim3(1536), dim3(256), 0, stream>>>(Xq, Xk, Xv, Wb, b_q, b_k, b_v,
                                                    Qw, Kw, Vw, qscale);
    k_attn<<<dim3(1024), dim3(512), 0, stream>>>(Qw, Kw, Vw, mb, Cw);
    k_oproj<<<dim3(512), dim3(256), 0, stream>>>(Cw, Wb + (3u << 20), b_o, out);
}

// Round 18
// 253.633 us; speedup vs baseline: 1.1415x; 1.0036x over previous
//
#include <hip/hip_runtime.h>
#include <hip/hip_bf16.h>
#include <stdint.h>

#define DM 1024
#define NHEADS 16
#define DK 64
#define BB 4
#define SS 2048

typedef unsigned short u16;
typedef __bf16 bf16x8 __attribute__((ext_vector_type(8)));
typedef __bf16 bf16x4 __attribute__((ext_vector_type(4)));
typedef float f32x4 __attribute__((ext_vector_type(4)));

#if __has_builtin(__builtin_amdgcn_exp2f)
#define EXP2(x) __builtin_amdgcn_exp2f(x)
#else
#define EXP2(x) exp2f(x)
#endif

static __device__ __forceinline__ u16 f2bf(float f) {
    union { float f; uint32_t u; } v; v.f = f;
    uint32_t r = v.u + 0x7fffu + ((v.u >> 16) & 1u);
    return (u16)(r >> 16);
}

static __device__ __forceinline__ f32x4 mfma16(bf16x8 a, bf16x8 b, f32x4 c) {
    return __builtin_amdgcn_mfma_f32_16x16x32_bf16(a, b, c, 0, 0, 0);
}

// async global->LDS 16B (linear LDS dest: wave-uniform base + lane*16)
static __device__ __forceinline__ void gload16(const u16* g, u16* l) {
    __builtin_amdgcn_global_load_lds((const __attribute__((address_space(1))) void*)g,
                                     (__attribute__((address_space(3))) void*)l, 16, 0, 0);
}

// ---------------- merged prep: weight cvt + X cvt + mask bit-pack ----------------
// ~35 us = HBM roofline (217 MB moved). R10/R11: fusing X-cvt or mask-pack into the
// GEMM both regressed (XCD panel re-fetch / L2 thrash) — keep prep separate.
#define PREP_W 4096
#define PREP_X 12288
#define PREP_M 2048
__global__ __launch_bounds__(256) void k_prep(const float* __restrict__ wq, const float* __restrict__ wk,
                                              const float* __restrict__ wv, const float* __restrict__ wo,
                                              u16* __restrict__ wout,
                                              const float* __restrict__ xq, const float* __restrict__ xk,
                                              const float* __restrict__ xv, u16* __restrict__ xout,
                                              const int* __restrict__ mask, uint32_t* __restrict__ bits) {
    const int bid = blockIdx.x, tid = threadIdx.x;
    if (bid < PREP_W) {
        int t = bid * 256 + tid;
        int which = t >> 18;
        int off = (t & 0x3FFFF) << 2;
        const float* src = (which == 0) ? wq : (which == 1) ? wk : (which == 2) ? wv : wo;
        float4 v = *(const float4*)(src + off);
        ushort4 o;
        o.x = f2bf(v.x); o.y = f2bf(v.y); o.z = f2bf(v.z); o.w = f2bf(v.w);
        *(ushort4*)(wout + ((size_t)which << 20) + off) = o;
    } else if (bid < PREP_W + PREP_X) {
        int lb = bid - PREP_W;
        int which = lb >> 12;
        const float* src = (which == 0) ? xq : (which == 1) ? xk : xv;
        size_t base = (((size_t)(lb & 4095)) * 256 + tid) * 8;
        float4 v0 = *(const float4*)(src + base);
        float4 v1 = *(const float4*)(src + base + 4);
        union { u16 s[8]; uint4 u; } p;
        p.s[0]=f2bf(v0.x); p.s[1]=f2bf(v0.y); p.s[2]=f2bf(v0.z); p.s[3]=f2bf(v0.w);
        p.s[4]=f2bf(v1.x); p.s[5]=f2bf(v1.y); p.s[6]=f2bf(v1.z); p.s[7]=f2bf(v1.w);
        *(uint4*)(xout + ((size_t)which << 23) + base) = p.u;
    } else {
        int lb = bid - PREP_W - PREP_X;
        int gid = lb * 256 + tid;
        int lane = gid & 63;
        int wv_ = gid >> 6;
        const int nw = (PREP_M * 256) >> 6;
        const long totalInts = (long)BB * SS * SS;
        for (long base = (long)wv_ * 64; base < totalInts; base += (long)nw * 64) {
            int m = mask[base + lane];
            unsigned long long bal = __ballot(m != 0);
            if (lane == 0)  bits[(base >> 5)]     = (uint32_t)bal;
            if (lane == 32) bits[(base >> 5) + 1] = (uint32_t)(bal >> 32);
        }
    }
}

// ---------------- 128x128-tile GEMM body, BK=64, XCD-local tile decode ----------------
// BK=64 (R16: half the barrier-drain events, -13.6 us) + both-sides XOR swizzle (rule #21).
// Tile decode m = tile&63, n = tile>>6 (T1, R17: -10.4 us): same-m blocks sit at bid
// stride 64 = 0 mod 8 -> SAME XCD; per-XCD set = 8 A-panels (2 MB) + W (2 MB) = its L2.
// T5 setprio around the MFMA cluster: free hint; likely null here (near-lockstep waves).
// MODE 0: Y bf16 [b][h][s][d] scaled. MODE 1: Y bf16 V^T [b][h][d][s]. MODE 2: f32 [m][n].
template<int MODE>
static __device__ __forceinline__ void gemm128(const u16* __restrict__ X, const u16* __restrict__ W,
                                               const float* __restrict__ bias, void* __restrict__ Yv,
                                               float alpha, int tile, int tid,
                                               u16* __restrict__ Ab, u16* __restrict__ Bb) {
    const int lane = tid & 63, w = tid >> 6;
    const int wr = w >> 1, wc = w & 1;
    const int lrow = lane & 15, lgrp = lane >> 4;
    const int m0 = (tile & 63) * 128;        // m-fastest: same-m blocks share an XCD
    const int n0 = (tile >> 6) * 128;
    const int sr = tid >> 3;                                  // row within 32-row group
    const int scol = (((tid & 7) ^ (sr & 7)) * 8);            // inverse-swizzled global col
    const int rswz = (lrow & 7) * 8;                          // read-side XOR (elems)

    f32x4 acc[4][4] = {};

    for (int kk = 0; kk < DM; kk += 64) {
#pragma unroll
        for (int i = 0; i < 4; ++i) {
            int row = i * 32 + sr;
            gload16(X + (size_t)(m0 + row) * DM + kk + scol, &Ab[i * 2048 + tid * 8]);
            gload16(W + (size_t)(n0 + row) * DM + kk + scol, &Bb[i * 2048 + tid * 8]);
        }
        __syncthreads();
#pragma unroll
        for (int kh = 0; kh < 2; ++kh) {
            bf16x8 af[4], bfr[4];
#pragma unroll
            for (int i = 0; i < 4; ++i)
                af[i] = *(const bf16x8*)&Ab[(wr * 64 + i * 16 + lrow) * 64 + ((kh * 32 + lgrp * 8) ^ rswz)];
#pragma unroll
            for (int j = 0; j < 4; ++j)
                bfr[j] = *(const bf16x8*)&Bb[(wc * 64 + j * 16 + lrow) * 64 + ((kh * 32 + lgrp * 8) ^ rswz)];
            __builtin_amdgcn_s_setprio(1);
#pragma unroll
            for (int i = 0; i < 4; ++i)
#pragma unroll
                for (int j = 0; j < 4; ++j)
                    acc[i][j] = mfma16(af[i], bfr[j], acc[i][j]);
            __builtin_amdgcn_s_setprio(0);
        }
        __syncthreads();
    }

#pragma unroll
    for (int j = 0; j < 4; ++j) {
        int n = n0 + wc * 64 + j * 16 + lrow;
        float bv_ = bias[n];
        int h = n >> 6, d = n & 63;
#pragma unroll
        for (int i = 0; i < 4; ++i) {
            int mbase = m0 + wr * 64 + i * 16 + (lgrp << 2);
            if (MODE == 0) {
                u16* Y = (u16*)Yv;
#pragma unroll
                for (int r = 0; r < 4; ++r) {
                    int m = mbase + r;
                    int b = m >> 11, s = m & 2047;
                    Y[(((size_t)(b * NHEADS + h) * SS) + s) * DK + d] = f2bf((acc[i][j][r] + bv_) * alpha);
                }
            } else if (MODE == 1) {
                int b = mbase >> 11, s = mbase & 2047;
                ushort4 o;
                o.x = f2bf(acc[i][j][0] + bv_);
                o.y = f2bf(acc[i][j][1] + bv_);
                o.z = f2bf(acc[i][j][2] + bv_);
                o.w = f2bf(acc[i][j][3] + bv_);
                *(ushort4*)&((u16*)Yv)[(((size_t)(b * NHEADS + h) * DK) + d) * SS + s] = o;
            } else {
                float* Y = (float*)Yv;
#pragma unroll
                for (int r = 0; r < 4; ++r)
                    Y[(size_t)(mbase + r) * DM + n] = acc[i][j][r] + bv_;
            }
        }
    }
}

// merged QKV: 1536 blocks, sel = bid>>9 in {0:Q, 1:K, 2:V^T}
__global__ __launch_bounds__(256) void k_projqkv(const u16* __restrict__ Xq, const u16* __restrict__ Xk,
                                                 const u16* __restrict__ Xv, const u16* __restrict__ Wb,
                                                 const float* __restrict__ bq, const float* __restrict__ bk,
                                                 const float* __restrict__ bv,
                                                 u16* __restrict__ Qw, u16* __restrict__ Kw,
                                                 u16* __restrict__ Vw, float qscale) {
    __shared__ u16 Ab[128 * 64];
    __shared__ u16 Bb[128 * 64];
    const int sel = blockIdx.x >> 9;
    const int tile = blockIdx.x & 511;
    if (sel == 0)      gemm128<0>(Xq, Wb,              bq, Qw, qscale, tile, threadIdx.x, Ab, Bb);
    else if (sel == 1) gemm128<0>(Xk, Wb + (1u << 20), bk, Kw, 1.0f,   tile, threadIdx.x, Ab, Bb);
    else               gemm128<1>(Xv, Wb + (2u << 20), bv, Vw, 1.0f,   tile, threadIdx.x, Ab, Bb);
}

// output projection: 512 blocks
__global__ __launch_bounds__(256) void k_oproj(const u16* __restrict__ X, const u16* __restrict__ W,
                                               const float* __restrict__ bias, float* __restrict__ out) {
    __shared__ u16 Ab[128 * 64];
    __shared__ u16 Bb[128 * 64];
    gemm128<2>(X, W, bias, out, 1.0f, blockIdx.x, threadIdx.x, Ab, Bb);
}

// ---------------- flash attention: R8 structure + T5 setprio ----------------
// 8 waves x 16 q-rows; KVBLK=64 double-buffered via global_load_lds; padded Pl.
// One barrier per kt -> waves drift within an iteration (softmax VALU vs QK/PV MFMA)
// -> T5's role-diversity prerequisite holds (m191: attn +4-7%); hint-only, zero risk.
// __launch_bounds__(512,4): do NOT raise min-waves (R6: (512,6) clamped VGPR to 40 -> spill).
#define NT (SS / 64)
__global__ __launch_bounds__(512, 4) void k_attn(const u16* __restrict__ Q, const u16* __restrict__ K,
                                                 const u16* __restrict__ VT, const uint32_t* __restrict__ mbits,
                                                 u16* __restrict__ ctx) {
    __shared__ u16 Kt[2][64 * 64];
    __shared__ u16 Vt[2][64 * 64];
    __shared__ u16 Pl[8][16][72];
    const int tid = threadIdx.x;
    const int lane = tid & 63, w = tid >> 6;
    const int lrow = lane & 15, lgrp = lane >> 4;
    const int bid = blockIdx.x;
    const int bh = bid & 63;
    const int qt = bid >> 6;          // [0,16)
    const int b = bh >> 4, h = bh & 15;
    const int qbase = qt * 128 + w * 16;

    const u16* Qh = Q + (size_t)bh * SS * DK;
    const u16* Kh = K + (size_t)bh * SS * DK;
    const u16* Vh = VT + (size_t)bh * DK * SS;

    bf16x8 qf0, qf1;
    {
        const u16* p = Qh + (size_t)(qbase + lrow) * DK + lgrp * 8;
        qf0 = *(const bf16x8*)(p);
        qf1 = *(const bf16x8*)(p + 32);
    }

    const uint64_t* mrow = (const uint64_t*)mbits + ((size_t)(b * SS + qbase + lrow)) * (SS / 64);

    union { uint4 u; bf16x8 v; } onesu;
    onesu.u = make_uint4(0x3F803F80u, 0x3F803F80u, 0x3F803F80u, 0x3F803F80u);
    const bf16x8 ones = onesu.v;

    // read-side swizzled col offsets for K/V tiles (elems), constant per lane
    const int swzA = (lgrp * 8) ^ ((lrow & 7) * 8);
    const int swzB = (32 + lgrp * 8) ^ ((lrow & 7) * 8);

    // staging: 512 threads, one 16B gload per thread per tile (K and V each)
    const int srow = tid >> 3;                           // 0..63
    const int ssrc = ((tid & 7) * 8) ^ ((srow & 7) * 8); // inverse swizzle on global col

    f32x4 acc[4] = {};   // [dt]
    f32x4 asum = {};

    // prologue: stage tile 0 into buffer 0
    gload16(Kh + (size_t)srow * DK + ssrc, &Kt[0][tid * 8]);
    gload16(Vh + (size_t)srow * SS + ssrc, &Vt[0][tid * 8]);
    __syncthreads();

    int cur = 0;
    for (int kt = 0; kt < NT; ++kt) {
        // phase A: issue next-tile staging (latency hides under compute)
        if (kt + 1 < NT) {
            gload16(Kh + (size_t)((kt + 1) * 64 + srow) * DK + ssrc, &Kt[cur ^ 1][tid * 8]);
            gload16(Vh + (size_t)srow * SS + (kt + 1) * 64 + ssrc, &Vt[cur ^ 1][tid * 8]);
        }
        const uint64_t wm = mrow[kt];

        const u16* Kc = Kt[cur];
        const u16* Vc = Vt[cur];
        // phase B: QK^T -> exp2+mask -> pack -> A-frags -> asum
        f32x4 st[4] = {};
        __builtin_amdgcn_s_setprio(1);
#pragma unroll
        for (int t = 0; t < 4; ++t) {
            bf16x8 ka = *(const bf16x8*)&Kc[(16 * t + lrow) * 64 + swzA];
            bf16x8 kb = *(const bf16x8*)&Kc[(16 * t + lrow) * 64 + swzB];
            st[t] = mfma16(ka, qf0, st[t]);
            st[t] = mfma16(kb, qf1, st[t]);
        }
        __builtin_amdgcn_s_setprio(0);
#pragma unroll
        for (int t = 0; t < 4; ++t) {
            uint32_t wt = (uint32_t)(wm >> (16 * t + 4 * lgrp));
            bf16x4 pk;
#pragma unroll
            for (int r = 0; r < 4; ++r) {
                float p = EXP2(st[t][r]);
                p = ((wt >> r) & 1u) ? p : 0.0f;
                pk[r] = (__bf16)p;
            }
            *(bf16x4*)&Pl[w][lrow][16 * t + 4 * lgrp] = pk;
        }
        bf16x8 pf0 = *(const bf16x8*)&Pl[w][lrow][lgrp * 8];
        bf16x8 pf1 = *(const bf16x8*)&Pl[w][lrow][32 + lgrp * 8];
        __builtin_amdgcn_s_setprio(1);
        asum = mfma16(pf0, ones, asum);
        asum = mfma16(pf1, ones, asum);
        // PV
#pragma unroll
        for (int dt = 0; dt < 4; ++dt) {
            bf16x8 vf0 = *(const bf16x8*)&Vc[(16 * dt + lrow) * 64 + swzA];
            bf16x8 vf1 = *(const bf16x8*)&Vc[(16 * dt + lrow) * 64 + swzB];
            acc[dt] = mfma16(pf0, vf0, acc[dt]);
            acc[dt] = mfma16(pf1, vf1, acc[dt]);
        }
        __builtin_amdgcn_s_setprio(0);
        // phase C: drain staging + sync all waves before buffer swap
        __syncthreads();
        cur ^= 1;
    }

    // epilogue: normalize (acc and asum share lane->q mapping) and write
#pragma unroll
    for (int r = 0; r < 4; ++r) {
        float li = 1.0f / asum[r];
        int q = qbase + 4 * lgrp + r;
#pragma unroll
        for (int dt = 0; dt < 4; ++dt)
            ctx[((size_t)b * SS + q) * DM + h * 64 + dt * 16 + lrow] = f2bf(acc[dt][r] * li);
    }
}

extern "C" void kernel_launch(void* const* d_in, const int* in_sizes, int n_in,
                              void* d_out, int out_size, void* d_ws, size_t ws_size,
                              hipStream_t stream) {
    const float* query = (const float*)d_in[0];
    const float* key   = (const float*)d_in[1];
    const float* value = (const float*)d_in[2];
    const int*   mask  = (const int*)d_in[3];
    const float* w_q   = (const float*)d_in[4];
    const float* b_q   = (const float*)d_in[5];
    const float* w_k   = (const float*)d_in[6];
    const float* b_k   = (const float*)d_in[7];
    const float* w_v   = (const float*)d_in[8];
    const float* b_v   = (const float*)d_in[9];
    const float* w_o   = (const float*)d_in[10];
    const float* b_o   = (const float*)d_in[11];
    float* out = (float*)d_out;

    char* ws = (char*)d_ws;
    u16*      Wb = (u16*)(ws);                      // 8 MiB: 4 x 1M bf16
    uint32_t* mb = (uint32_t*)(ws + (8u  << 20));   // 2 MiB packed mask bits
    u16*      Xq = (u16*)(ws + (16u << 20));        // 16 MiB each
    u16*      Xk = (u16*)(ws + (32u << 20));
    u16*      Xv = (u16*)(ws + (48u << 20));
    u16*      Qw = (u16*)(ws + (64u << 20));
    u16*      Kw = (u16*)(ws + (80u << 20));
    u16*      Vw = (u16*)(ws + (96u << 20));        // V transposed
    u16*      Cw = (u16*)(ws + (112u << 20));       // context

    const float qscale = 0.125f * 1.4426950408889634f;  // 1/sqrt(64) * log2(e)

    k_prep<<<dim3(PREP_W + PREP_X + PREP_M), dim3(256), 0, stream>>>(
        w_q, w_k, w_v, w_o, Wb, query, key, value, Xq, mask, mb);
    k_projqkv<<<dim3(1536), dim3(256), 0, stream>>>(Xq, Xk, Xv, Wb, b_q, b_k, b_v,
                                                    Qw, Kw, Vw, qscale);
    k_attn<<<dim3(1024), dim3(512), 0, stream>>>(Qw, Kw, Vw, mb, Cw);
    k_oproj<<<dim3(512), dim3(256), 0, stream>>>(Cw, Wb + (3u << 20), b_o, out);
}

// Round 19
// 252.825 us; speedup vs baseline: 1.1451x; 1.0032x over previous
//
#include <hip/hip_runtime.h>
#include <hip/hip_bf16.h>
#include <stdint.h>

#define DM 1024
#define NHEADS 16
#define DK 64
#define BB 4
#define SS 2048

typedef unsigned short u16;
typedef __bf16 bf16x8 __attribute__((ext_vector_type(8)));
typedef __bf16 bf16x4 __attribute__((ext_vector_type(4)));
typedef float f32x4 __attribute__((ext_vector_type(4)));

#if __has_builtin(__builtin_amdgcn_exp2f)
#define EXP2(x) __builtin_amdgcn_exp2f(x)
#else
#define EXP2(x) exp2f(x)
#endif

static __device__ __forceinline__ u16 f2bf(float f) {
    union { float f; uint32_t u; } v; v.f = f;
    uint32_t r = v.u + 0x7fffu + ((v.u >> 16) & 1u);
    return (u16)(r >> 16);
}

static __device__ __forceinline__ f32x4 mfma16(bf16x8 a, bf16x8 b, f32x4 c) {
    return __builtin_amdgcn_mfma_f32_16x16x32_bf16(a, b, c, 0, 0, 0);
}

// async global->LDS 16B (linear LDS dest: wave-uniform base + lane*16)
static __device__ __forceinline__ void gload16(const u16* g, u16* l) {
    __builtin_amdgcn_global_load_lds((const __attribute__((address_space(1))) void*)g,
                                     (__attribute__((address_space(3))) void*)l, 16, 0, 0);
}

// ---------------- merged prep: weight cvt + X cvt + mask bit-pack ----------------
// ~35 us = HBM roofline (217 MB moved). R10/R11: fusing X-cvt or mask-pack into the
// GEMM both regressed (XCD panel re-fetch / L2 thrash) — keep prep separate.
#define PREP_W 4096
#define PREP_X 12288
#define PREP_M 2048
__global__ __launch_bounds__(256) void k_prep(const float* __restrict__ wq, const float* __restrict__ wk,
                                              const float* __restrict__ wv, const float* __restrict__ wo,
                                              u16* __restrict__ wout,
                                              const float* __restrict__ xq, const float* __restrict__ xk,
                                              const float* __restrict__ xv, u16* __restrict__ xout,
                                              const int* __restrict__ mask, uint32_t* __restrict__ bits) {
    const int bid = blockIdx.x, tid = threadIdx.x;
    if (bid < PREP_W) {
        int t = bid * 256 + tid;
        int which = t >> 18;
        int off = (t & 0x3FFFF) << 2;
        const float* src = (which == 0) ? wq : (which == 1) ? wk : (which == 2) ? wv : wo;
        float4 v = *(const float4*)(src + off);
        ushort4 o;
        o.x = f2bf(v.x); o.y = f2bf(v.y); o.z = f2bf(v.z); o.w = f2bf(v.w);
        *(ushort4*)(wout + ((size_t)which << 20) + off) = o;
    } else if (bid < PREP_W + PREP_X) {
        int lb = bid - PREP_W;
        int which = lb >> 12;
        const float* src = (which == 0) ? xq : (which == 1) ? xk : xv;
        size_t base = (((size_t)(lb & 4095)) * 256 + tid) * 8;
        float4 v0 = *(const float4*)(src + base);
        float4 v1 = *(const float4*)(src + base + 4);
        union { u16 s[8]; uint4 u; } p;
        p.s[0]=f2bf(v0.x); p.s[1]=f2bf(v0.y); p.s[2]=f2bf(v0.z); p.s[3]=f2bf(v0.w);
        p.s[4]=f2bf(v1.x); p.s[5]=f2bf(v1.y); p.s[6]=f2bf(v1.z); p.s[7]=f2bf(v1.w);
        *(uint4*)(xout + ((size_t)which << 23) + base) = p.u;
    } else {
        int lb = bid - PREP_W - PREP_X;
        int gid = lb * 256 + tid;
        int lane = gid & 63;
        int wv_ = gid >> 6;
        const int nw = (PREP_M * 256) >> 6;
        const long totalInts = (long)BB * SS * SS;
        for (long base = (long)wv_ * 64; base < totalInts; base += (long)nw * 64) {
            int m = mask[base + lane];
            unsigned long long bal = __ballot(m != 0);
            if (lane == 0)  bits[(base >> 5)]     = (uint32_t)bal;
            if (lane == 32) bits[(base >> 5) + 1] = (uint32_t)(bal >> 32);
        }
    }
}

// ---------------- 128x128-tile GEMM body, BK=64, XCD-local decode, setprio ----------------
// BK=64 (R16: half the barrier-drain events, -13.6 us) + both-sides XOR swizzle (rule #21).
// Tile decode m = tile&63, n = tile>>6 (T1, R17: -10.4 us): same-m blocks share an XCD;
// per-XCD set = 8 A-panels (2 MB) + W (2 MB) = its 4 MB L2.
// T5 setprio around MFMA cluster: R18 A/B showed ~4-5 us combined GEMM gain (waves drift
// across the two barriers per K-step -> role diversity). Kept HERE; removed from attn
// (R18: attn 121.4->124.8 regression with setprio).
// MODE 0: Y bf16 [b][h][s][d] scaled. MODE 1: Y bf16 V^T [b][h][d][s]. MODE 2: f32 [m][n].
template<int MODE>
static __device__ __forceinline__ void gemm128(const u16* __restrict__ X, const u16* __restrict__ W,
                                               const float* __restrict__ bias, void* __restrict__ Yv,
                                               float alpha, int tile, int tid,
                                               u16* __restrict__ Ab, u16* __restrict__ Bb) {
    const int lane = tid & 63, w = tid >> 6;
    const int wr = w >> 1, wc = w & 1;
    const int lrow = lane & 15, lgrp = lane >> 4;
    const int m0 = (tile & 63) * 128;        // m-fastest: same-m blocks share an XCD
    const int n0 = (tile >> 6) * 128;
    const int sr = tid >> 3;                                  // row within 32-row group
    const int scol = (((tid & 7) ^ (sr & 7)) * 8);            // inverse-swizzled global col
    const int rswz = (lrow & 7) * 8;                          // read-side XOR (elems)

    f32x4 acc[4][4] = {};

    for (int kk = 0; kk < DM; kk += 64) {
#pragma unroll
        for (int i = 0; i < 4; ++i) {
            int row = i * 32 + sr;
            gload16(X + (size_t)(m0 + row) * DM + kk + scol, &Ab[i * 2048 + tid * 8]);
            gload16(W + (size_t)(n0 + row) * DM + kk + scol, &Bb[i * 2048 + tid * 8]);
        }
        __syncthreads();
#pragma unroll
        for (int kh = 0; kh < 2; ++kh) {
            bf16x8 af[4], bfr[4];
#pragma unroll
            for (int i = 0; i < 4; ++i)
                af[i] = *(const bf16x8*)&Ab[(wr * 64 + i * 16 + lrow) * 64 + ((kh * 32 + lgrp * 8) ^ rswz)];
#pragma unroll
            for (int j = 0; j < 4; ++j)
                bfr[j] = *(const bf16x8*)&Bb[(wc * 64 + j * 16 + lrow) * 64 + ((kh * 32 + lgrp * 8) ^ rswz)];
            __builtin_amdgcn_s_setprio(1);
#pragma unroll
            for (int i = 0; i < 4; ++i)
#pragma unroll
                for (int j = 0; j < 4; ++j)
                    acc[i][j] = mfma16(af[i], bfr[j], acc[i][j]);
            __builtin_amdgcn_s_setprio(0);
        }
        __syncthreads();
    }

#pragma unroll
    for (int j = 0; j < 4; ++j) {
        int n = n0 + wc * 64 + j * 16 + lrow;
        float bv_ = bias[n];
        int h = n >> 6, d = n & 63;
#pragma unroll
        for (int i = 0; i < 4; ++i) {
            int mbase = m0 + wr * 64 + i * 16 + (lgrp << 2);
            if (MODE == 0) {
                u16* Y = (u16*)Yv;
#pragma unroll
                for (int r = 0; r < 4; ++r) {
                    int m = mbase + r;
                    int b = m >> 11, s = m & 2047;
                    Y[(((size_t)(b * NHEADS + h) * SS) + s) * DK + d] = f2bf((acc[i][j][r] + bv_) * alpha);
                }
            } else if (MODE == 1) {
                int b = mbase >> 11, s = mbase & 2047;
                ushort4 o;
                o.x = f2bf(acc[i][j][0] + bv_);
                o.y = f2bf(acc[i][j][1] + bv_);
                o.z = f2bf(acc[i][j][2] + bv_);
                o.w = f2bf(acc[i][j][3] + bv_);
                *(ushort4*)&((u16*)Yv)[(((size_t)(b * NHEADS + h) * DK) + d) * SS + s] = o;
            } else {
                float* Y = (float*)Yv;
#pragma unroll
                for (int r = 0; r < 4; ++r)
                    Y[(size_t)(mbase + r) * DM + n] = acc[i][j][r] + bv_;
            }
        }
    }
}

// merged QKV: 1536 blocks, sel = bid>>9 in {0:Q, 1:K, 2:V^T}
__global__ __launch_bounds__(256) void k_projqkv(const u16* __restrict__ Xq, const u16* __restrict__ Xk,
                                                 const u16* __restrict__ Xv, const u16* __restrict__ Wb,
                                                 const float* __restrict__ bq, const float* __restrict__ bk,
                                                 const float* __restrict__ bv,
                                                 u16* __restrict__ Qw, u16* __restrict__ Kw,
                                                 u16* __restrict__ Vw, float qscale) {
    __shared__ u16 Ab[128 * 64];
    __shared__ u16 Bb[128 * 64];
    const int sel = blockIdx.x >> 9;
    const int tile = blockIdx.x & 511;
    if (sel == 0)      gemm128<0>(Xq, Wb,              bq, Qw, qscale, tile, threadIdx.x, Ab, Bb);
    else if (sel == 1) gemm128<0>(Xk, Wb + (1u << 20), bk, Kw, 1.0f,   tile, threadIdx.x, Ab, Bb);
    else               gemm128<1>(Xv, Wb + (2u << 20), bv, Vw, 1.0f,   tile, threadIdx.x, Ab, Bb);
}

// output projection: 512 blocks
__global__ __launch_bounds__(256) void k_oproj(const u16* __restrict__ X, const u16* __restrict__ W,
                                               const float* __restrict__ bias, float* __restrict__ out) {
    __shared__ u16 Ab[128 * 64];
    __shared__ u16 Bb[128 * 64];
    gemm128<2>(X, W, bias, out, 1.0f, blockIdx.x, threadIdx.x, Ab, Bb);
}

// ---------------- flash attention: R8 version EXACT (best measured: 121.4 us) ----------------
// 8 waves x 16 q-rows; KVBLK=64 double-buffered via global_load_lds; padded Pl. NO setprio
// (R18 A/B: setprio here regressed 121.4->124.8 — boosted MFMA waves starve softmax peers).
// Plateau evidence: 9 variants all 121-130 us -> structure-stable optimum.
// __launch_bounds__(512,4): do NOT raise min-waves (R6: (512,6) clamped VGPR to 40 -> spill).
#define NT (SS / 64)
__global__ __launch_bounds__(512, 4) void k_attn(const u16* __restrict__ Q, const u16* __restrict__ K,
                                                 const u16* __restrict__ VT, const uint32_t* __restrict__ mbits,
                                                 u16* __restrict__ ctx) {
    __shared__ u16 Kt[2][64 * 64];
    __shared__ u16 Vt[2][64 * 64];
    __shared__ u16 Pl[8][16][72];
    const int tid = threadIdx.x;
    const int lane = tid & 63, w = tid >> 6;
    const int lrow = lane & 15, lgrp = lane >> 4;
    const int bid = blockIdx.x;
    const int bh = bid & 63;
    const int qt = bid >> 6;          // [0,16)
    const int b = bh >> 4, h = bh & 15;
    const int qbase = qt * 128 + w * 16;

    const u16* Qh = Q + (size_t)bh * SS * DK;
    const u16* Kh = K + (size_t)bh * SS * DK;
    const u16* Vh = VT + (size_t)bh * DK * SS;

    bf16x8 qf0, qf1;
    {
        const u16* p = Qh + (size_t)(qbase + lrow) * DK + lgrp * 8;
        qf0 = *(const bf16x8*)(p);
        qf1 = *(const bf16x8*)(p + 32);
    }

    const uint64_t* mrow = (const uint64_t*)mbits + ((size_t)(b * SS + qbase + lrow)) * (SS / 64);

    union { uint4 u; bf16x8 v; } onesu;
    onesu.u = make_uint4(0x3F803F80u, 0x3F803F80u, 0x3F803F80u, 0x3F803F80u);
    const bf16x8 ones = onesu.v;

    // read-side swizzled col offsets for K/V tiles (elems), constant per lane
    const int swzA = (lgrp * 8) ^ ((lrow & 7) * 8);
    const int swzB = (32 + lgrp * 8) ^ ((lrow & 7) * 8);

    // staging: 512 threads, one 16B gload per thread per tile (K and V each)
    const int srow = tid >> 3;                           // 0..63
    const int ssrc = ((tid & 7) * 8) ^ ((srow & 7) * 8); // inverse swizzle on global col

    f32x4 acc[4] = {};   // [dt]
    f32x4 asum = {};

    // prologue: stage tile 0 into buffer 0
    gload16(Kh + (size_t)srow * DK + ssrc, &Kt[0][tid * 8]);
    gload16(Vh + (size_t)srow * SS + ssrc, &Vt[0][tid * 8]);
    __syncthreads();

    int cur = 0;
    for (int kt = 0; kt < NT; ++kt) {
        // phase A: issue next-tile staging (latency hides under compute)
        if (kt + 1 < NT) {
            gload16(Kh + (size_t)((kt + 1) * 64 + srow) * DK + ssrc, &Kt[cur ^ 1][tid * 8]);
            gload16(Vh + (size_t)srow * SS + (kt + 1) * 64 + ssrc, &Vt[cur ^ 1][tid * 8]);
        }
        const uint64_t wm = mrow[kt];

        const u16* Kc = Kt[cur];
        const u16* Vc = Vt[cur];
        // phase B: QK^T -> exp2+mask -> pack -> A-frags -> asum
        f32x4 st[4] = {};
#pragma unroll
        for (int t = 0; t < 4; ++t) {
            bf16x8 ka = *(const bf16x8*)&Kc[(16 * t + lrow) * 64 + swzA];
            bf16x8 kb = *(const bf16x8*)&Kc[(16 * t + lrow) * 64 + swzB];
            st[t] = mfma16(ka, qf0, st[t]);
            st[t] = mfma16(kb, qf1, st[t]);
        }
#pragma unroll
        for (int t = 0; t < 4; ++t) {
            uint32_t wt = (uint32_t)(wm >> (16 * t + 4 * lgrp));
            bf16x4 pk;
#pragma unroll
            for (int r = 0; r < 4; ++r) {
                float p = EXP2(st[t][r]);
                p = ((wt >> r) & 1u) ? p : 0.0f;
                pk[r] = (__bf16)p;
            }
            *(bf16x4*)&Pl[w][lrow][16 * t + 4 * lgrp] = pk;
        }
        bf16x8 pf0 = *(const bf16x8*)&Pl[w][lrow][lgrp * 8];
        bf16x8 pf1 = *(const bf16x8*)&Pl[w][lrow][32 + lgrp * 8];
        asum = mfma16(pf0, ones, asum);
        asum = mfma16(pf1, ones, asum);
        // PV
#pragma unroll
        for (int dt = 0; dt < 4; ++dt) {
            bf16x8 vf0 = *(const bf16x8*)&Vc[(16 * dt + lrow) * 64 + swzA];
            bf16x8 vf1 = *(const bf16x8*)&Vc[(16 * dt + lrow) * 64 + swzB];
            acc[dt] = mfma16(pf0, vf0, acc[dt]);
            acc[dt] = mfma16(pf1, vf1, acc[dt]);
        }
        // phase C: drain staging + sync all waves before buffer swap
        __syncthreads();
        cur ^= 1;
    }

    // epilogue: normalize (acc and asum share lane->q mapping) and write
#pragma unroll
    for (int r = 0; r < 4; ++r) {
        float li = 1.0f / asum[r];
        int q = qbase + 4 * lgrp + r;
#pragma unroll
        for (int dt = 0; dt < 4; ++dt)
            ctx[((size_t)b * SS + q) * DM + h * 64 + dt * 16 + lrow] = f2bf(acc[dt][r] * li);
    }
}

extern "C" void kernel_launch(void* const* d_in, const int* in_sizes, int n_in,
                              void* d_out, int out_size, void* d_ws, size_t ws_size,
                              hipStream_t stream) {
    const float* query = (const float*)d_in[0];
    const float* key   = (const float*)d_in[1];
    const float* value = (const float*)d_in[2];
    const int*   mask  = (const int*)d_in[3];
    const float* w_q   = (const float*)d_in[4];
    const float* b_q   = (const float*)d_in[5];
    const float* w_k   = (const float*)d_in[6];
    const float* b_k   = (const float*)d_in[7];
    const float* w_v   = (const float*)d_in[8];
    const float* b_v   = (const float*)d_in[9];
    const float* w_o   = (const float*)d_in[10];
    const float* b_o   = (const float*)d_in[11];
    float* out = (float*)d_out;

    char* ws = (char*)d_ws;
    u16*      Wb = (u16*)(ws);                      // 8 MiB: 4 x 1M bf16
    uint32_t* mb = (uint32_t*)(ws + (8u  << 20));   // 2 MiB packed mask bits
    u16*      Xq = (u16*)(ws + (16u << 20));        // 16 MiB each
    u16*      Xk = (u16*)(ws + (32u << 20));
    u16*      Xv = (u16*)(ws + (48u << 20));
    u16*      Qw = (u16*)(ws + (64u << 20));
    u16*      Kw = (u16*)(ws + (80u << 20));
    u16*      Vw = (u16*)(ws + (96u << 20));        // V transposed
    u16*      Cw = (u16*)(ws + (112u << 20));       // context

    const float qscale = 0.125f * 1.4426950408889634f;  // 1/sqrt(64) * log2(e)

    k_prep<<<dim3(PREP_W + PREP_X + PREP_M), dim3(256), 0, stream>>>(
        w_q, w_k, w_v, w_o, Wb, query, key, value, Xq, mask, mb);
    k_projqkv<<<dim3(1536), dim3(256), 0, stream>>>(Xq, Xk, Xv, Wb, b_q, b_k, b_v,
                                                    Qw, Kw, Vw, qscale);
    k_attn<<<dim3(1024), dim3(512), 0, stream>>>(Qw, Kw, Vw, mb, Cw);
    k_oproj<<<dim3(512), dim3(256), 0, stream>>>(Cw, Wb + (3u << 20), b_o, out);
}